// Round 10
// baseline (540.617 us; speedup 1.0000x reference)
//
#include <hip/hip_runtime.h>
#include <cstdint>
#include <cstddef>

// Problem constants
#define Bn 16
#define Sn 2048
#define Hn 1024
#define Nn 2048   // n_examples * mem_len

typedef unsigned short u16;
typedef __bf16 bf16x8 __attribute__((ext_vector_type(8)));
typedef float  f32x4  __attribute__((ext_vector_type(4)));
typedef int    i32x4  __attribute__((ext_vector_type(4)));
typedef short  s16x8  __attribute__((ext_vector_type(8)));
typedef unsigned short u16x8 __attribute__((ext_vector_type(8)));
typedef unsigned int   u32x4 __attribute__((ext_vector_type(4)));
typedef unsigned char  u8x4  __attribute__((ext_vector_type(4)));
typedef unsigned char  u8x8  __attribute__((ext_vector_type(8)));

__device__ __forceinline__ u16 f2bf(float f) {        // RNE float->bf16
  unsigned u = __builtin_bit_cast(unsigned, f);
  u += 0x7fffu + ((u >> 16) & 1u);
  return (u16)(u >> 16);
}

// Two-level int8 quantization: x ~ (q1 + q2/128)/16, q1,q2 in [-127,127].
__device__ __forceinline__ void quant2(float x, char& q1, char& q2) {
  float f1 = rintf(x * 16.f);
  f1 = fminf(127.f, fmaxf(-127.f, f1));
  float r = x - f1 * 0.0625f;
  float f2 = rintf(r * 2048.f);
  f2 = fminf(127.f, fmaxf(-127.f, f2));
  q1 = (char)(int)f1;
  q2 = (char)(int)f2;
}

// Single-level i8 x16 (for GEMM2's mem operand; max err 1/32).
__device__ __forceinline__ char quant1(float x) {
  float f = rintf(x * 16.f);
  f = fminf(127.f, fmaxf(-127.f, f));
  return (char)(int)f;
}

// Stage 16 rows x 64B (one global_load_lds_dwordx4 per lane, LDS dest linear
// base + lane*16). Global source granule XOR-swizzled with (row>>1)&3 so the
// ds_read side (same XOR) is bank-conflict-free (both-sides rule #21).
__device__ __forceinline__ void stage64Bb(const char* gbase, int pitchBytes, void* ldsbase, int lane) {
  const int gsrc = (lane & 3) ^ ((lane >> 3) & 3);   // g ^ ((row_local>>1)&3), row_local = lane>>2
  const char* gp = gbase + (size_t)(lane >> 2) * pitchBytes + gsrc * 16;
  __builtin_amdgcn_global_load_lds(
      (__attribute__((address_space(1))) void*)gp,
      (__attribute__((address_space(3))) void*)ldsbase, 16, 0, 0);
}

// ---------------- prep kernels (batch-chunk local) ----------------

// seq fp32 -> two-level i8, 4 per thread.
__global__ __launch_bounds__(256) void prep_seq_i8(const float* __restrict__ seq,
                                                   char* __restrict__ a1, char* __restrict__ a2) {
  size_t i = (size_t)blockIdx.x * 256 + threadIdx.x;
  float4 v = ((const float4*)seq)[i];
  float x[4] = {v.x, v.y, v.z, v.w};
  u8x4 p1, p2;
#pragma unroll
  for (int j = 0; j < 4; ++j) {
    char q1, q2;
    quant2(x[j], q1, q2);
    p1[j] = (unsigned char)q1;
    p2[j] = (unsigned char)q2;
  }
  ((u8x4*)a1)[i] = p1;
  ((u8x4*)a2)[i] = p2;
}

// Fused memory prep: reads each mem element ONCE (as the [N][H] view), emits
//  bt1[n'][h'] i8 two-level  where flat[h'*2048+n'] = flat[r*1024+c]
//    (n' = (r&1)*1024 + c, h' = r>>1; mask index = 2h'+(n'>>10) = r)
//  bt2[h][n]  i8 x16         (transpose of the natural [N][H] view; mask mk[n])
__global__ __launch_bounds__(256) void prep_bt(const float* __restrict__ mem,
                                               const int* __restrict__ mmask,
                                               char* __restrict__ b1o, char* __restrict__ b2o,
                                               char* __restrict__ bt2) {
  __shared__ float tile[64][33];
  const int b = blockIdx.z;
  const int r0 = blockIdx.x * 64;   // 32 blocks
  const int c0 = blockIdx.y * 32;   // 32 blocks
  const int tx = threadIdx.x & 31, ty = threadIdx.x >> 5;   // 32 x 8
  const float* src = mem + (size_t)b * (Nn * Hn);
  const int* mk = mmask + b * Nn;
#pragma unroll
  for (int j = 0; j < 8; ++j) {
    int r = r0 + ty + j * 8;
    float v = src[(size_t)r * Hn + c0 + tx];
    v = mk[r] ? v : 0.f;
    tile[ty + j * 8][tx] = v;
  }
  __syncthreads();
  // bt2: h = c0 + hl (32 rows), n = r0 + n8*8 + j (64 cols); 8 i8 per thread
  {
    const int hl = threadIdx.x & 31;
    const int n8 = threadIdx.x >> 5;
    u8x8 ov;
#pragma unroll
    for (int j = 0; j < 8; ++j) ov[j] = (unsigned char)quant1(tile[n8 * 8 + j][hl]);
    *(u8x8*)(bt2 + (size_t)b * Hn * Nn + (size_t)(c0 + hl) * Nn + r0 + n8 * 8) = ov;
  }
  // bt1: n' = p*1024 + c0 + cl, h' = r0/2 + q*8 + j; 8 i8 pairs per thread
  {
    const int cl = threadIdx.x & 31;
    const int p  = (threadIdx.x >> 5) & 1;
    const int q  = threadIdx.x >> 6;          // 0..3
    u8x8 o1, o2;
#pragma unroll
    for (int j = 0; j < 8; ++j) {
      char q1, q2;
      quant2(tile[2 * (q * 8 + j) + p][cl], q1, q2);
      o1[j] = (unsigned char)q1;
      o2[j] = (unsigned char)q2;
    }
    size_t o = (size_t)b * Nn * Hn + (size_t)(p * 1024 + c0 + cl) * Hn + (r0 >> 1) + q * 8;
    *(u8x8*)(b1o + o) = o1;
    *(u8x8*)(b2o + o) = o2;
  }
}

// ---------------- GEMM1 v3: scores via two-level i8 split ----------------
// 128x128 tile, BK=64, 4 waves (2x2). TRI-buffered LDS {A1|B1|B2} (3 x 24KB),
// prefetch distance 2, raw s_barrier with NO vmcnt drain: stage(k+1) landing
// is transitively guaranteed by the compiler's register-dep vmcnt before C2
// (A2(k) global loads sit after stage(k+1) in the FIFO). A2 comes from L2
// straight to registers (parallel pipe, 16B/lane), cutting LDS-port traffic.
__global__ __launch_bounds__(256, 2) void gemm_scores(
    const char* __restrict__ A1, const char* __restrict__ A2,
    const char* __restrict__ B1, const char* __restrict__ B2,
    short* __restrict__ C) {
  __shared__ __align__(16) char ldsm[73728];   // 3 x 24KB: [A1 8K | B1 8K | B2 8K]
  const int b = blockIdx.z;
  // XCD-aware remap: each XCD's blocks form an 8(tn) x 4(tm) rectangle.
  const int lid = blockIdx.x + (blockIdx.y << 4);
  const int xcd = lid & 7, idx = lid >> 3;
  const int tn = ((xcd & 1) << 3) | (idx & 7);
  const int tm = ((xcd >> 1) << 2) | (idx >> 3);
  const int tid = threadIdx.x;
  const int w = tid >> 6, l = tid & 63;
  const int wr = w >> 1, wc = w & 1;
  const size_t aOff = (size_t)(b * Sn + tm * 128) * Hn;
  const size_t bOff = (size_t)(b * Nn + tn * 128) * Hn;

  i32x4 acc1[4][4] = {};
  i32x4 acc2[4][4] = {};

  const int gRd = ((l >> 4) ^ ((l >> 1) & 3)) * 16;
  const int ao = (wr * 64 + (l & 15)) * 64 + gRd;
  const int bo = (wc * 64 + (l & 15)) * 64 + gRd;

  // wave w stages 6 16-row groups of the concat row-space [A1:128|B1:128|B2:128]
  auto stageStep = [&](int kk, char* buf) {
    const int kb = kk * 64;
#pragma unroll
    for (int i = 0; i < 6; ++i) {
      const int r = w * 96 + i * 16;
      const char* src;
      if (r < 128)      src = A1 + aOff + (size_t)r * Hn + kb;
      else if (r < 256) src = B1 + bOff + (size_t)(r - 128) * Hn + kb;
      else              src = B2 + bOff + (size_t)(r - 256) * Hn + kb;
      stage64Bb(src, Hn, buf + r * 64, l);
    }
  };

  // per-lane A2 global fragment address (row = wr*64 + mi*16 + (l&15), 16B at (l>>4)*16)
  const char* a2base = A2 + aOff + (size_t)(wr * 64 + (l & 15)) * Hn + (l >> 4) * 16;

  stageStep(0, ldsm);
  stageStep(1, ldsm + 24576);
  i32x4 a2r[4];
#pragma unroll
  for (int mi = 0; mi < 4; ++mi)
    a2r[mi] = *(const i32x4*)(a2base + (size_t)mi * 16 * Hn);
  __syncthreads();

  int cb = 0;
  for (int kk = 0; kk < 16; ++kk) {
    char* cur = ldsm + cb * 24576;
    int sb = cb + 2; if (sb >= 3) sb -= 3;
    if (kk + 2 < 16) stageStep(kk + 2, ldsm + sb * 24576);
    // C1: acc1 += a1*b1
    i32x4 a1f[4], b1f[4];
#pragma unroll
    for (int ni = 0; ni < 4; ++ni) b1f[ni] = *(const i32x4*)(cur + 8192 + bo + ni * 1024);
#pragma unroll
    for (int mi = 0; mi < 4; ++mi) a1f[mi] = *(const i32x4*)(cur + ao + mi * 1024);
    __builtin_amdgcn_s_setprio(1);
#pragma unroll
    for (int mi = 0; mi < 4; ++mi)
#pragma unroll
      for (int ni = 0; ni < 4; ++ni)
        acc1[mi][ni] = __builtin_amdgcn_mfma_i32_16x16x64_i8(a1f[mi], b1f[ni], acc1[mi][ni], 0, 0, 0);
    // C2: acc2 += a2r*b1  (a2r loaded from global last step; its vmcnt wait
    // transitively drains this step's buffer staging -> barrier needs no drain)
#pragma unroll
    for (int mi = 0; mi < 4; ++mi)
#pragma unroll
      for (int ni = 0; ni < 4; ++ni)
        acc2[mi][ni] = __builtin_amdgcn_mfma_i32_16x16x64_i8(a2r[mi], b1f[ni], acc2[mi][ni], 0, 0, 0);
    __builtin_amdgcn_s_setprio(0);
    // issue A2(k+1) -> regs
    i32x4 a2n[4];
    if (kk + 1 < 16) {
      const int kb1 = (kk + 1) * 64;
#pragma unroll
      for (int mi = 0; mi < 4; ++mi)
        a2n[mi] = *(const i32x4*)(a2base + (size_t)mi * 16 * Hn + kb1);
    }
    // C3: acc2 += a1*b2 (a1 re-read from LDS to cap VGPR below the 256 cliff)
    i32x4 b2f[4], a1g[4];
#pragma unroll
    for (int ni = 0; ni < 4; ++ni) b2f[ni] = *(const i32x4*)(cur + 16384 + bo + ni * 1024);
#pragma unroll
    for (int mi = 0; mi < 4; ++mi) a1g[mi] = *(const i32x4*)(cur + ao + mi * 1024);
    __builtin_amdgcn_s_setprio(1);
#pragma unroll
    for (int mi = 0; mi < 4; ++mi)
#pragma unroll
      for (int ni = 0; ni < 4; ++ni)
        acc2[mi][ni] = __builtin_amdgcn_mfma_i32_16x16x64_i8(a1g[mi], b2f[ni], acc2[mi][ni], 0, 0, 0);
    __builtin_amdgcn_s_setprio(0);
    if (kk + 1 < 16) {
#pragma unroll
      for (int mi = 0; mi < 4; ++mi) a2r[mi] = a2n[mi];
      __builtin_amdgcn_s_barrier();
      __builtin_amdgcn_sched_barrier(0);
    }
    cb = (cb + 1 == 3) ? 0 : cb + 1;
  }
  // scores_fixed = (128*acc1 + acc2) / 256  (= true_score * 128), i16.
  const int r0 = tm * 128 + wr * 64 + (l >> 4) * 4;
  const int c0 = tn * 128 + wc * 64 + (l & 15);
#pragma unroll
  for (int mi = 0; mi < 4; ++mi)
#pragma unroll
    for (int ni = 0; ni < 4; ++ni) {
      size_t base = (size_t)(b * Sn + r0 + mi * 16) * Nn + c0 + ni * 16;
#pragma unroll
      for (int j = 0; j < 4; ++j) {
        int t = acc1[mi][ni][j] * 128 + acc2[mi][ni][j];
        int s = (int)rintf((float)t * (1.f / 256.f));
        s = s > 32767 ? 32767 : (s < -32767 ? -32767 : s);
        C[base + (size_t)j * Nn] = (short)s;
      }
    }
}

// ---------------- softmax over N on i16 scores (x128); u8 probs (x127) out ----------------
__global__ __launch_bounds__(256) void softmax_rows(const short* __restrict__ sc,
                                                    unsigned char* __restrict__ p8) {
  __shared__ float red[8];
  const size_t row = blockIdx.x;
  const short* p = sc + row * Nn;
  const int t = threadIdx.x;
  s16x8 v = ((const s16x8*)p)[t];
  float x[8];
#pragma unroll
  for (int j = 0; j < 8; ++j) x[j] = (float)v[j] * 0.0078125f;  // /128
  float m = x[0];
#pragma unroll
  for (int j = 1; j < 8; ++j) m = fmaxf(m, x[j]);
  for (int o = 32; o > 0; o >>= 1) m = fmaxf(m, __shfl_xor(m, o));
  if ((t & 63) == 0) red[t >> 6] = m;
  __syncthreads();
  m = fmaxf(fmaxf(red[0], red[1]), fmaxf(red[2], red[3]));
  float e[8], s = 0.f;
#pragma unroll
  for (int j = 0; j < 8; ++j) { e[j] = __expf(x[j] - m); s += e[j]; }
  for (int o = 32; o > 0; o >>= 1) s += __shfl_xor(s, o);
  if ((t & 63) == 0) red[4 + (t >> 6)] = s;
  __syncthreads();
  s = (red[4] + red[5]) + (red[6] + red[7]);
  const float inv = 127.f / s;
  u8x8 ob;
#pragma unroll
  for (int j = 0; j < 8; ++j) ob[j] = (unsigned char)(int)rintf(e[j] * inv);
  *(u8x8*)(p8 + row * Nn + t * 8) = ob;
}

// ---------------- GEMM2: out = seq + probs @ mem, single-level i8 ----------------
// 128x128 tile, BK=64 (i8 K=64/instr), dbuf 2 x 16KB = 32KB LDS, 3 blocks/CU.
// out = seq + acc / (127*16).
__global__ __launch_bounds__(256, 3) void gemm_attn(
    const char* __restrict__ P8,  // u8 probs x127, pitch 2048
    const char* __restrict__ Bt,  // i8 mem^T x16, [BC][1024][2048]
    const float* __restrict__ seq, float* __restrict__ out) {
  __shared__ __align__(16) char ldsm[32768];   // 2 buffers x {A 8KB, B 8KB}
  const int b = blockIdx.z;
  // XCD remap: grid (8,16); each XCD gets a 4(tn) x 4(tm) rectangle.
  const int lid = blockIdx.x + (blockIdx.y << 3);
  const int xcd = lid & 7, idx = lid >> 3;
  const int tn = ((xcd & 1) << 2) | (idx & 3);
  const int tm = ((xcd >> 1) << 2) | (idx >> 2);
  const int tid = threadIdx.x;
  const int w = tid >> 6, l = tid & 63;
  const int wr = w >> 1, wc = w & 1;
  const size_t aOff = (size_t)(b * Sn + tm * 128) * Nn;   // bytes, pitch 2048
  const size_t bOff = (size_t)(b * Hn + tn * 128) * Nn;

  i32x4 acc[4][4] = {};

  const int gRd = ((l >> 4) ^ ((l >> 1) & 3)) * 16;
  const int ao = (wr * 64 + (l & 15)) * 64 + gRd;
  const int bo = (wc * 64 + (l & 15)) * 64 + gRd;

  auto stageStep = [&](int kk, char* buf) {
    const int kb = kk * 64;
#pragma unroll
    for (int i = 0; i < 2; ++i) {
      const int rb = w * 32 + i * 16;
      stage64Bb(P8 + aOff + (size_t)rb * Nn + kb, Nn, buf + rb * 64, l);
      stage64Bb(Bt + bOff + (size_t)rb * Nn + kb, Nn, buf + 8192 + rb * 64, l);
    }
  };

  stageStep(0, ldsm);
  __syncthreads();

  for (int kk = 0; kk < Nn / 64; ++kk) {   // 32 K-steps
    char* cur = ldsm + (kk & 1) * 16384;
    if (kk < Nn / 64 - 1) stageStep(kk + 1, ldsm + ((kk + 1) & 1) * 16384);
    i32x4 bfr[4];
#pragma unroll
    for (int ni = 0; ni < 4; ++ni) bfr[ni] = *(const i32x4*)(cur + 8192 + bo + ni * 1024);
    i32x4 afr[4];
#pragma unroll
    for (int mi = 0; mi < 4; ++mi) afr[mi] = *(const i32x4*)(cur + ao + mi * 1024);
    __builtin_amdgcn_s_setprio(1);
#pragma unroll
    for (int mi = 0; mi < 4; ++mi)
#pragma unroll
      for (int ni = 0; ni < 4; ++ni)
        acc[mi][ni] = __builtin_amdgcn_mfma_i32_16x16x64_i8(afr[mi], bfr[ni], acc[mi][ni], 0, 0, 0);
    __builtin_amdgcn_s_setprio(0);
    if (kk < Nn / 64 - 1) __syncthreads();
  }
  const int r0 = tm * 128 + wr * 64 + (l >> 4) * 4;
  const int c0 = tn * 128 + wc * 64 + (l & 15);
  const float scl = 1.f / 2032.f;   // 1/(127*16)
#pragma unroll
  for (int mi = 0; mi < 4; ++mi)
#pragma unroll
    for (int ni = 0; ni < 4; ++ni) {
      size_t base = (size_t)(b * Sn + r0 + mi * 16) * Hn + c0 + ni * 16;
      out[base]          = seq[base]          + (float)acc[mi][ni][0] * scl;
      out[base + Hn]     = seq[base + Hn]     + (float)acc[mi][ni][1] * scl;
      out[base + 2 * Hn] = seq[base + 2 * Hn] + (float)acc[mi][ni][2] * scl;
      out[base + 3 * Hn] = seq[base + 3 * Hn] + (float)acc[mi][ni][3] * scl;
    }
}

// Distinctive fill if ws is too small: absmax ~12345 tells us it was this guard.
__global__ void ws_fail(float* out) {
  size_t i = (size_t)blockIdx.x * blockDim.x + threadIdx.x;
  size_t stride = (size_t)gridDim.x * blockDim.x;
  for (; i < (size_t)Bn * Sn * Hn; i += stride) out[i] = 12345.0f;
}

extern "C" void kernel_launch(void* const* d_in, const int* in_sizes, int n_in,
                              void* d_out, int out_size, void* d_ws, size_t ws_size,
                              hipStream_t stream) {
  const float* seq = (const float*)d_in[0];
  // d_in[1] (attention_mask) is unused by the reference
  const float* mem = (const float*)d_in[2];
  const int* mmask = (const int*)d_in[3];
  float* out = (float*)d_out;

  // Per-batch: a1,a2,b1,b2 (4x2 MiB) + bt2 i8 (2 MiB) + scores i16 (8 MiB) + p8 (4 MiB) = 22 MiB
  const size_t MiB = 1024 * 1024;
  const size_t perB = 22 * MiB;
  int BC = 16;
  while (BC > 1 && (size_t)BC * perB > ws_size) BC >>= 1;
  if ((size_t)BC * perB > ws_size) {
    ws_fail<<<2048, 256, 0, stream>>>(out);
    return;
  }

  char* ws = (char*)d_ws;
  const size_t SEG8 = (size_t)BC * Sn * Hn;       // BC * 2 MiB
  char* a1 = ws;
  char* a2 = ws + SEG8;
  char* b1 = ws + 2 * SEG8;
  char* b2 = ws + 3 * SEG8;
  char* bt2 = ws + 4 * SEG8;                      // 1 SEG8
  short* scores = (short*)(ws + 5 * SEG8);        // 4 SEG8 (BC x 8 MiB)
  unsigned char* p8 = (unsigned char*)(ws + 9 * SEG8);  // 2 SEG8 (BC x 4 MiB)

  for (int b0 = 0; b0 < Bn; b0 += BC) {
    const float* seqb = seq + (size_t)b0 * Sn * Hn;
    const float* memb = mem + (size_t)b0 * Nn * Hn;
    const int* mkb = mmask + (size_t)b0 * Nn;
    float* outb = out + (size_t)b0 * Sn * Hn;

    prep_seq_i8<<<dim3(BC * Sn * Hn / 4 / 256), 256, 0, stream>>>(seqb, a1, a2);
    prep_bt<<<dim3(Nn / 64, Hn / 32, BC), 256, 0, stream>>>(memb, mkb, b1, b2, bt2);
    gemm_scores<<<dim3(Nn / 128, Sn / 128, BC), 256, 0, stream>>>(a1, a2, b1, b2, scores);
    softmax_rows<<<dim3(BC * Sn), 256, 0, stream>>>(scores, p8);
    gemm_attn<<<dim3(Hn / 128, Sn / 128, BC), 256, 0, stream>>>((const char*)p8, bt2, seqb, outb);
  }
}

// Round 11
// 487.160 us; speedup vs baseline: 1.1097x; 1.1097x over previous
//
#include <hip/hip_runtime.h>
#include <cstdint>
#include <cstddef>

// Problem constants
#define Bn 16
#define Sn 2048
#define Hn 1024
#define Nn 2048   // n_examples * mem_len

typedef unsigned short u16;
typedef __bf16 bf16x8 __attribute__((ext_vector_type(8)));
typedef float  f32x4  __attribute__((ext_vector_type(4)));
typedef int    i32x4  __attribute__((ext_vector_type(4)));
typedef short  s16x8  __attribute__((ext_vector_type(8)));
typedef unsigned short u16x8 __attribute__((ext_vector_type(8)));
typedef unsigned int   u32x4 __attribute__((ext_vector_type(4)));
typedef unsigned char  u8x4  __attribute__((ext_vector_type(4)));
typedef unsigned char  u8x8  __attribute__((ext_vector_type(8)));

// Two-level int8 quantization: x ~ (q1 + q2/128)/16, q1,q2 in [-127,127].
__device__ __forceinline__ void quant2(float x, char& q1, char& q2) {
  float f1 = rintf(x * 16.f);
  f1 = fminf(127.f, fmaxf(-127.f, f1));
  float r = x - f1 * 0.0625f;
  float f2 = rintf(r * 2048.f);
  f2 = fminf(127.f, fmaxf(-127.f, f2));
  q1 = (char)(int)f1;
  q2 = (char)(int)f2;
}

// Single-level i8 x16 (for GEMM2's mem operand; max err 1/32).
__device__ __forceinline__ char quant1(float x) {
  float f = rintf(x * 16.f);
  f = fminf(127.f, fmaxf(-127.f, f));
  return (char)(int)f;
}

// Stage 16 rows x 64B (one global_load_lds_dwordx4 per lane, LDS dest linear
// base + lane*16). Global source granule XOR-swizzled with (row>>1)&3 so the
// ds_read side (same XOR) is bank-conflict-free (both-sides rule #21).
__device__ __forceinline__ void stage64Bb(const char* gbase, int pitchBytes, void* ldsbase, int lane) {
  const int gsrc = (lane & 3) ^ ((lane >> 3) & 3);   // g ^ ((row_local>>1)&3), row_local = lane>>2
  const char* gp = gbase + (size_t)(lane >> 2) * pitchBytes + gsrc * 16;
  __builtin_amdgcn_global_load_lds(
      (__attribute__((address_space(1))) void*)gp,
      (__attribute__((address_space(3))) void*)ldsbase, 16, 0, 0);
}

// ---------------- prep kernels (batch-chunk local) ----------------

// seq fp32 -> two-level i8, 4 per thread.
__global__ __launch_bounds__(256) void prep_seq_i8(const float* __restrict__ seq,
                                                   char* __restrict__ a1, char* __restrict__ a2) {
  size_t i = (size_t)blockIdx.x * 256 + threadIdx.x;
  float4 v = ((const float4*)seq)[i];
  float x[4] = {v.x, v.y, v.z, v.w};
  u8x4 p1, p2;
#pragma unroll
  for (int j = 0; j < 4; ++j) {
    char q1, q2;
    quant2(x[j], q1, q2);
    p1[j] = (unsigned char)q1;
    p2[j] = (unsigned char)q2;
  }
  ((u8x4*)a1)[i] = p1;
  ((u8x4*)a2)[i] = p2;
}

// Fused memory prep: reads each mem element ONCE (as the [N][H] view), emits
//  bt1[n'][h'] i8 two-level  where flat[h'*2048+n'] = flat[r*1024+c]
//    (n' = (r&1)*1024 + c, h' = r>>1; mask index = 2h'+(n'>>10) = r)
//  bt2[h][n]  i8 x16         (transpose of the natural [N][H] view; mask mk[n])
__global__ __launch_bounds__(256) void prep_bt(const float* __restrict__ mem,
                                               const int* __restrict__ mmask,
                                               char* __restrict__ b1o, char* __restrict__ b2o,
                                               char* __restrict__ bt2) {
  __shared__ float tile[64][33];
  const int b = blockIdx.z;
  const int r0 = blockIdx.x * 64;   // 32 blocks
  const int c0 = blockIdx.y * 32;   // 32 blocks
  const int tx = threadIdx.x & 31, ty = threadIdx.x >> 5;   // 32 x 8
  const float* src = mem + (size_t)b * (Nn * Hn);
  const int* mk = mmask + b * Nn;
#pragma unroll
  for (int j = 0; j < 8; ++j) {
    int r = r0 + ty + j * 8;
    float v = src[(size_t)r * Hn + c0 + tx];
    v = mk[r] ? v : 0.f;
    tile[ty + j * 8][tx] = v;
  }
  __syncthreads();
  // bt2: region 32 h x 64 n. Lane mapping for coalesced writes: 8 lanes cover
  // 64 contiguous n-bytes of one h-row (h = t>>3, n-off = (t&7)*8).
  {
    const int hh = threadIdx.x >> 3;          // 0..31
    const int nb = (threadIdx.x & 7) * 8;     // 0..56
    u8x8 ov;
#pragma unroll
    for (int j = 0; j < 8; ++j) ov[j] = (unsigned char)quant1(tile[nb + j][hh]);
    *(u8x8*)(bt2 + (size_t)b * Hn * Nn + (size_t)(c0 + hh) * Nn + r0 + nb) = ov;
  }
  // bt1: n' = p*1024 + c0 + cl, h' = r0/2 + q*8 + j; 8 i8 pairs per thread
  // (4 consecutive lanes = 32 contiguous bytes of one n'-row).
  {
    const int cl = threadIdx.x & 31;
    const int p  = (threadIdx.x >> 5) & 1;
    const int q  = threadIdx.x >> 6;          // 0..3
    u8x8 o1, o2;
#pragma unroll
    for (int j = 0; j < 8; ++j) {
      char q1, q2;
      quant2(tile[2 * (q * 8 + j) + p][cl], q1, q2);
      o1[j] = (unsigned char)q1;
      o2[j] = (unsigned char)q2;
    }
    size_t o = (size_t)b * Nn * Hn + (size_t)(p * 1024 + c0 + cl) * Hn + (r0 >> 1) + q * 8;
    *(u8x8*)(b1o + o) = o1;
    *(u8x8*)(b2o + o) = o2;
  }
}

// ---------------- GEMM1: scores via two-level i8 split (R9 proven version) ----------------
// 128x128 tile, BK=64, 4 waves (2x2). Double-buffered LDS (2 x 32KB), one
// barrier per K-step. a1 frags cached in VGPR across both passes. i16 output.
__global__ __launch_bounds__(256, 2) void gemm_scores(
    const char* __restrict__ A1, const char* __restrict__ A2,
    const char* __restrict__ B1, const char* __restrict__ B2,
    short* __restrict__ C) {
  __shared__ __align__(16) char ldsm[65536];   // 2 buffers x {LA1,LA2,LB1,LB2} x 8KB
  const int b = blockIdx.z;
  // XCD-aware remap: each XCD's blocks form an 8(tn) x 4(tm) rectangle.
  const int lid = blockIdx.x + (blockIdx.y << 4);
  const int xcd = lid & 7, idx = lid >> 3;
  const int tn = ((xcd & 1) << 3) | (idx & 7);
  const int tm = ((xcd >> 1) << 2) | (idx >> 3);
  const int tid = threadIdx.x;
  const int w = tid >> 6, l = tid & 63;
  const int wr = w >> 1, wc = w & 1;
  const size_t aOff = (size_t)(b * Sn + tm * 128) * Hn;
  const size_t bOff = (size_t)(b * Nn + tn * 128) * Hn;

  i32x4 acc1[4][4] = {};
  i32x4 acc2[4][4] = {};

  const int gRd = ((l >> 4) ^ ((l >> 1) & 3)) * 16;
  const int ao = (wr * 64 + (l & 15)) * 64 + gRd;
  const int bo = (wc * 64 + (l & 15)) * 64 + gRd;

  auto stageStep = [&](int kk, char* buf) {
    const int kb = kk * 64;
#pragma unroll
    for (int i = 0; i < 2; ++i) {
      const int rb = w * 32 + i * 16;
      const size_t ro = (size_t)rb * Hn + kb;
      stage64Bb(A1 + aOff + ro, Hn, buf + rb * 64, l);
      stage64Bb(A2 + aOff + ro, Hn, buf + 8192 + rb * 64, l);
      stage64Bb(B1 + bOff + ro, Hn, buf + 16384 + rb * 64, l);
      stage64Bb(B2 + bOff + ro, Hn, buf + 24576 + rb * 64, l);
    }
  };

  stageStep(0, ldsm);
  __syncthreads();

  for (int kk = 0; kk < Hn / 64; ++kk) {   // 16 K-steps
    char* cur = ldsm + (kk & 1) * 32768;
    if (kk < Hn / 64 - 1) stageStep(kk + 1, ldsm + ((kk + 1) & 1) * 32768);
    i32x4 a1c[4];
    // Pass 1: b1 against a1 (->acc1) and a2 (->acc2); a1 kept in regs
    {
      i32x4 bf[4];
#pragma unroll
      for (int ni = 0; ni < 4; ++ni) bf[ni] = *(const i32x4*)(cur + 16384 + bo + ni * 1024);
#pragma unroll
      for (int mi = 0; mi < 4; ++mi) {
        a1c[mi] = *(const i32x4*)(cur + ao + mi * 1024);
        i32x4 a2f = *(const i32x4*)(cur + 8192 + ao + mi * 1024);
#pragma unroll
        for (int ni = 0; ni < 4; ++ni) {
          acc1[mi][ni] = __builtin_amdgcn_mfma_i32_16x16x64_i8(a1c[mi], bf[ni], acc1[mi][ni], 0, 0, 0);
          acc2[mi][ni] = __builtin_amdgcn_mfma_i32_16x16x64_i8(a2f, bf[ni], acc2[mi][ni], 0, 0, 0);
        }
      }
    }
    // Pass 2: b2 against cached a1 (->acc2)
    {
      i32x4 bf[4];
#pragma unroll
      for (int ni = 0; ni < 4; ++ni) bf[ni] = *(const i32x4*)(cur + 24576 + bo + ni * 1024);
#pragma unroll
      for (int mi = 0; mi < 4; ++mi)
#pragma unroll
        for (int ni = 0; ni < 4; ++ni)
          acc2[mi][ni] = __builtin_amdgcn_mfma_i32_16x16x64_i8(a1c[mi], bf[ni], acc2[mi][ni], 0, 0, 0);
    }
    if (kk < Hn / 64 - 1) __syncthreads();
  }
  // scores_fixed = (128*acc1 + acc2) / 256  (= true_score * 128), i16.
  const int r0 = tm * 128 + wr * 64 + (l >> 4) * 4;
  const int c0 = tn * 128 + wc * 64 + (l & 15);
#pragma unroll
  for (int mi = 0; mi < 4; ++mi)
#pragma unroll
    for (int ni = 0; ni < 4; ++ni) {
      size_t base = (size_t)(b * Sn + r0 + mi * 16) * Nn + c0 + ni * 16;
#pragma unroll
      for (int j = 0; j < 4; ++j) {
        int t = acc1[mi][ni][j] * 128 + acc2[mi][ni][j];
        int s = (int)rintf((float)t * (1.f / 256.f));
        s = s > 32767 ? 32767 : (s < -32767 ? -32767 : s);
        C[base + (size_t)j * Nn] = (short)s;
      }
    }
}

// ---------------- softmax over N on i16 scores (x128); u8 probs (x127) out ----------------
__global__ __launch_bounds__(256) void softmax_rows(const short* __restrict__ sc,
                                                    unsigned char* __restrict__ p8) {
  __shared__ float red[8];
  const size_t row = blockIdx.x;
  const short* p = sc + row * Nn;
  const int t = threadIdx.x;
  s16x8 v = ((const s16x8*)p)[t];
  float x[8];
#pragma unroll
  for (int j = 0; j < 8; ++j) x[j] = (float)v[j] * 0.0078125f;  // /128
  float m = x[0];
#pragma unroll
  for (int j = 1; j < 8; ++j) m = fmaxf(m, x[j]);
  for (int o = 32; o > 0; o >>= 1) m = fmaxf(m, __shfl_xor(m, o));
  if ((t & 63) == 0) red[t >> 6] = m;
  __syncthreads();
  m = fmaxf(fmaxf(red[0], red[1]), fmaxf(red[2], red[3]));
  float e[8], s = 0.f;
#pragma unroll
  for (int j = 0; j < 8; ++j) { e[j] = __expf(x[j] - m); s += e[j]; }
  for (int o = 32; o > 0; o >>= 1) s += __shfl_xor(s, o);
  if ((t & 63) == 0) red[4 + (t >> 6)] = s;
  __syncthreads();
  s = (red[4] + red[5]) + (red[6] + red[7]);
  const float inv = 127.f / s;
  u8x8 ob;
#pragma unroll
  for (int j = 0; j < 8; ++j) ob[j] = (unsigned char)(int)rintf(e[j] * inv);
  *(u8x8*)(p8 + row * Nn + t * 8) = ob;
}

// ---------------- GEMM2: out = residual + probs @ mem, single-level i8 ----------------
// 128x128 tile, BK=64 (i8 K=64/instr), dbuf 2 x 16KB = 32KB LDS, 3 blocks/CU.
// Residual reconstructed from a1/a2 (seq ~ a1/16 + a2/2048, err <= 1/4096):
// saves the fp32 seq re-read (67 MB) in the epilogue.
__global__ __launch_bounds__(256, 3) void gemm_attn(
    const char* __restrict__ P8,  // u8 probs x127, pitch 2048
    const char* __restrict__ Bt,  // i8 mem^T x16, [BC][1024][2048]
    const char* __restrict__ A1q, const char* __restrict__ A2q,
    float* __restrict__ out) {
  __shared__ __align__(16) char ldsm[32768];   // 2 buffers x {A 8KB, B 8KB}
  const int b = blockIdx.z;
  // XCD remap: grid (8,16); each XCD gets a 4(tn) x 4(tm) rectangle.
  const int lid = blockIdx.x + (blockIdx.y << 3);
  const int xcd = lid & 7, idx = lid >> 3;
  const int tn = ((xcd & 1) << 2) | (idx & 3);
  const int tm = ((xcd >> 1) << 2) | (idx >> 2);
  const int tid = threadIdx.x;
  const int w = tid >> 6, l = tid & 63;
  const int wr = w >> 1, wc = w & 1;
  const size_t aOff = (size_t)(b * Sn + tm * 128) * Nn;   // bytes, pitch 2048
  const size_t bOff = (size_t)(b * Hn + tn * 128) * Nn;

  i32x4 acc[4][4] = {};

  const int gRd = ((l >> 4) ^ ((l >> 1) & 3)) * 16;
  const int ao = (wr * 64 + (l & 15)) * 64 + gRd;
  const int bo = (wc * 64 + (l & 15)) * 64 + gRd;

  auto stageStep = [&](int kk, char* buf) {
    const int kb = kk * 64;
#pragma unroll
    for (int i = 0; i < 2; ++i) {
      const int rb = w * 32 + i * 16;
      stage64Bb(P8 + aOff + (size_t)rb * Nn + kb, Nn, buf + rb * 64, l);
      stage64Bb(Bt + bOff + (size_t)rb * Nn + kb, Nn, buf + 8192 + rb * 64, l);
    }
  };

  stageStep(0, ldsm);
  __syncthreads();

  for (int kk = 0; kk < Nn / 64; ++kk) {   // 32 K-steps
    char* cur = ldsm + (kk & 1) * 16384;
    if (kk < Nn / 64 - 1) stageStep(kk + 1, ldsm + ((kk + 1) & 1) * 16384);
    i32x4 bfr[4];
#pragma unroll
    for (int ni = 0; ni < 4; ++ni) bfr[ni] = *(const i32x4*)(cur + 8192 + bo + ni * 1024);
    i32x4 afr[4];
#pragma unroll
    for (int mi = 0; mi < 4; ++mi) afr[mi] = *(const i32x4*)(cur + ao + mi * 1024);
    __builtin_amdgcn_s_setprio(1);
#pragma unroll
    for (int mi = 0; mi < 4; ++mi)
#pragma unroll
      for (int ni = 0; ni < 4; ++ni)
        acc[mi][ni] = __builtin_amdgcn_mfma_i32_16x16x64_i8(afr[mi], bfr[ni], acc[mi][ni], 0, 0, 0);
    __builtin_amdgcn_s_setprio(0);
    if (kk < Nn / 64 - 1) __syncthreads();
  }
  const int r0 = tm * 128 + wr * 64 + (l >> 4) * 4;
  const int c0 = tn * 128 + wc * 64 + (l & 15);
  const float scl = 1.f / 2032.f;   // 1/(127*16)
#pragma unroll
  for (int mi = 0; mi < 4; ++mi)
#pragma unroll
    for (int ni = 0; ni < 4; ++ni) {
      size_t base = (size_t)(b * Sn + r0 + mi * 16) * Hn + c0 + ni * 16;
#pragma unroll
      for (int j = 0; j < 4; ++j) {
        size_t idx2 = base + (size_t)j * Hn;
        float res = (float)A1q[idx2] * 0.0625f + (float)A2q[idx2] * (1.f / 2048.f);
        out[idx2] = res + (float)acc[mi][ni][j] * scl;
      }
    }
}

// Distinctive fill if ws is too small: absmax ~12345 tells us it was this guard.
__global__ void ws_fail(float* out) {
  size_t i = (size_t)blockIdx.x * blockDim.x + threadIdx.x;
  size_t stride = (size_t)gridDim.x * blockDim.x;
  for (; i < (size_t)Bn * Sn * Hn; i += stride) out[i] = 12345.0f;
}

extern "C" void kernel_launch(void* const* d_in, const int* in_sizes, int n_in,
                              void* d_out, int out_size, void* d_ws, size_t ws_size,
                              hipStream_t stream) {
  const float* seq = (const float*)d_in[0];
  // d_in[1] (attention_mask) is unused by the reference
  const float* mem = (const float*)d_in[2];
  const int* mmask = (const int*)d_in[3];
  float* out = (float*)d_out;

  // Per-batch: a1,a2,b1,b2 (4x2 MiB) + bt2 i8 (2 MiB) + scores i16 (8 MiB) + p8 (4 MiB) = 22 MiB
  const size_t MiB = 1024 * 1024;
  const size_t perB = 22 * MiB;
  int BC = 16;
  while (BC > 1 && (size_t)BC * perB > ws_size) BC >>= 1;
  if ((size_t)BC * perB > ws_size) {
    ws_fail<<<2048, 256, 0, stream>>>(out);
    return;
  }

  char* ws = (char*)d_ws;
  const size_t SEG8 = (size_t)BC * Sn * Hn;       // BC * 2 MiB
  char* a1 = ws;
  char* a2 = ws + SEG8;
  char* b1 = ws + 2 * SEG8;
  char* b2 = ws + 3 * SEG8;
  char* bt2 = ws + 4 * SEG8;                      // 1 SEG8
  short* scores = (short*)(ws + 5 * SEG8);        // 4 SEG8 (BC x 8 MiB)
  unsigned char* p8 = (unsigned char*)(ws + 9 * SEG8);  // 2 SEG8 (BC x 4 MiB)

  for (int b0 = 0; b0 < Bn; b0 += BC) {
    const float* seqb = seq + (size_t)b0 * Sn * Hn;
    const float* memb = mem + (size_t)b0 * Nn * Hn;
    const int* mkb = mmask + (size_t)b0 * Nn;
    float* outb = out + (size_t)b0 * Sn * Hn;

    prep_seq_i8<<<dim3(BC * Sn * Hn / 4 / 256), 256, 0, stream>>>(seqb, a1, a2);
    prep_bt<<<dim3(Nn / 64, Hn / 32, BC), 256, 0, stream>>>(memb, mkb, b1, b2, bt2);
    gemm_scores<<<dim3(Nn / 128, Sn / 128, BC), 256, 0, stream>>>(a1, a2, b1, b2, scores);
    softmax_rows<<<dim3(BC * Sn), 256, 0, stream>>>(scores, p8);
    gemm_attn<<<dim3(Hn / 128, Sn / 128, BC), 256, 0, stream>>>((const char*)p8, bt2, a1, a2, outb);
  }
}

// Round 12
// 482.598 us; speedup vs baseline: 1.1202x; 1.0095x over previous
//
#include <hip/hip_runtime.h>
#include <cstdint>
#include <cstddef>

// Problem constants
#define Bn 16
#define Sn 2048
#define Hn 1024
#define Nn 2048   // n_examples * mem_len

typedef unsigned short u16;
typedef float  f32x4  __attribute__((ext_vector_type(4)));
typedef int    i32x4  __attribute__((ext_vector_type(4)));
typedef short  s16x8  __attribute__((ext_vector_type(8)));
typedef unsigned char  u8x4  __attribute__((ext_vector_type(4)));
typedef unsigned char  u8x8  __attribute__((ext_vector_type(8)));

// Two-level int8 quantization: x ~ (q1 + q2/128)/16, q1,q2 in [-127,127].
__device__ __forceinline__ void quant2(float x, char& q1, char& q2) {
  float f1 = rintf(x * 16.f);
  f1 = fminf(127.f, fmaxf(-127.f, f1));
  float r = x - f1 * 0.0625f;
  float f2 = rintf(r * 2048.f);
  f2 = fminf(127.f, fmaxf(-127.f, f2));
  q1 = (char)(int)f1;
  q2 = (char)(int)f2;
}

// Single-level i8 x16 (for GEMM2's mem operand; max err 1/32).
__device__ __forceinline__ char quant1(float x) {
  float f = rintf(x * 16.f);
  f = fminf(127.f, fmaxf(-127.f, f));
  return (char)(int)f;
}

// Stage 16 rows x 64B (one global_load_lds_dwordx4 per lane, LDS dest linear
// base + lane*16). Global source granule XOR-swizzled with (row>>1)&3 so the
// ds_read side (same XOR) is bank-conflict-free (both-sides rule #21).
__device__ __forceinline__ void stage64Bb(const char* gbase, int pitchBytes, void* ldsbase, int lane) {
  const int gsrc = (lane & 3) ^ ((lane >> 3) & 3);   // g ^ ((row_local>>1)&3), row_local = lane>>2
  const char* gp = gbase + (size_t)(lane >> 2) * pitchBytes + gsrc * 16;
  __builtin_amdgcn_global_load_lds(
      (__attribute__((address_space(1))) void*)gp,
      (__attribute__((address_space(3))) void*)ldsbase, 16, 0, 0);
}

// ---------------- prep kernels (batch-chunk local) ----------------

// seq fp32 -> two-level i8, 4 per thread.
__global__ __launch_bounds__(256) void prep_seq_i8(const float* __restrict__ seq,
                                                   char* __restrict__ a1, char* __restrict__ a2) {
  size_t i = (size_t)blockIdx.x * 256 + threadIdx.x;
  float4 v = ((const float4*)seq)[i];
  float x[4] = {v.x, v.y, v.z, v.w};
  u8x4 p1, p2;
#pragma unroll
  for (int j = 0; j < 4; ++j) {
    char q1, q2;
    quant2(x[j], q1, q2);
    p1[j] = (unsigned char)q1;
    p2[j] = (unsigned char)q2;
  }
  ((u8x4*)a1)[i] = p1;
  ((u8x4*)a2)[i] = p2;
}

// Fused memory prep: reads each mem element ONCE (as the [N][H] view), emits
//  bt1[n'][h'] i8 two-level  where flat[h'*2048+n'] = flat[r*1024+c]
//    (n' = (r&1)*1024 + c, h' = r>>1; mask index = 2h'+(n'>>10) = r)
//  bt2[h][n]  i8 x16         (transpose of the natural [N][H] view; mask mk[n])
__global__ __launch_bounds__(256) void prep_bt(const float* __restrict__ mem,
                                               const int* __restrict__ mmask,
                                               char* __restrict__ b1o, char* __restrict__ b2o,
                                               char* __restrict__ bt2) {
  __shared__ float tile[64][33];
  const int b = blockIdx.z;
  const int r0 = blockIdx.x * 64;   // 32 blocks
  const int c0 = blockIdx.y * 32;   // 32 blocks
  const int tx = threadIdx.x & 31, ty = threadIdx.x >> 5;   // 32 x 8
  const float* src = mem + (size_t)b * (Nn * Hn);
  const int* mk = mmask + b * Nn;
#pragma unroll
  for (int j = 0; j < 8; ++j) {
    int r = r0 + ty + j * 8;
    float v = src[(size_t)r * Hn + c0 + tx];
    v = mk[r] ? v : 0.f;
    tile[ty + j * 8][tx] = v;
  }
  __syncthreads();
  // bt2: region 32 h x 64 n. Lane mapping for coalesced writes: 8 lanes cover
  // 64 contiguous n-bytes of one h-row (h = t>>3, n-off = (t&7)*8).
  {
    const int hh = threadIdx.x >> 3;          // 0..31
    const int nb = (threadIdx.x & 7) * 8;     // 0..56
    u8x8 ov;
#pragma unroll
    for (int j = 0; j < 8; ++j) ov[j] = (unsigned char)quant1(tile[nb + j][hh]);
    *(u8x8*)(bt2 + (size_t)b * Hn * Nn + (size_t)(c0 + hh) * Nn + r0 + nb) = ov;
  }
  // bt1: n' = p*1024 + c0 + cl, h' = r0/2 + q*8 + j; 8 i8 pairs per thread
  {
    const int cl = threadIdx.x & 31;
    const int p  = (threadIdx.x >> 5) & 1;
    const int q  = threadIdx.x >> 6;          // 0..3
    u8x8 o1, o2;
#pragma unroll
    for (int j = 0; j < 8; ++j) {
      char q1, q2;
      quant2(tile[2 * (q * 8 + j) + p][cl], q1, q2);
      o1[j] = (unsigned char)q1;
      o2[j] = (unsigned char)q2;
    }
    size_t o = (size_t)b * Nn * Hn + (size_t)(p * 1024 + c0 + cl) * Hn + (r0 >> 1) + q * 8;
    *(u8x8*)(b1o + o) = o1;
    *(u8x8*)(b2o + o) = o2;
  }
}

// ---------------- GEMM1: scores, 3-phase T3+T4 schedule ----------------
// 128x128 tile, BK=64, 4 waves (2x2), dbuf 2x32KB (2 blocks/CU preserved).
// Per K-tile, 3 phases (one MFMA cluster each): C1 a1*b1, C2 a2*b1, C3 a1*b2.
// Stage of tile k+1 split into halves H1={A1,B1}(4 loads), H2={A2}(2),
// H3={B2}(2), issued one per phase -> every load flies a FULL K-tile before
// use. Phase-entry waits are counted (vmcnt 4/6/6, never 0 in steady state);
// vmcnt precedes s_barrier so the all-waves guarantee holds transitively.
__global__ __launch_bounds__(256, 2) void gemm_scores(
    const char* __restrict__ A1, const char* __restrict__ A2,
    const char* __restrict__ B1, const char* __restrict__ B2,
    short* __restrict__ C) {
  __shared__ __align__(16) char ldsm[65536];   // 2 buffers x {LA1|LA2|LB1|LB2} x 8KB
  const int b = blockIdx.z;
  // XCD-aware remap: each XCD's blocks form an 8(tn) x 4(tm) rectangle.
  const int lid = blockIdx.x + (blockIdx.y << 4);
  const int xcd = lid & 7, idx = lid >> 3;
  const int tn = ((xcd & 1) << 3) | (idx & 7);
  const int tm = ((xcd >> 1) << 2) | (idx >> 3);
  const int tid = threadIdx.x;
  const int w = tid >> 6, l = tid & 63;
  const int wr = w >> 1, wc = w & 1;
  const size_t aOff = (size_t)(b * Sn + tm * 128) * Hn;
  const size_t bOff = (size_t)(b * Nn + tn * 128) * Hn;

  i32x4 acc1[4][4] = {};
  i32x4 acc2[4][4] = {};

  const int gRd = ((l >> 4) ^ ((l >> 1) & 3)) * 16;
  const int ao = (wr * 64 + (l & 15)) * 64 + gRd;
  const int bo = (wc * 64 + (l & 15)) * 64 + gRd;

  // Per-wave stage halves (wave w owns rows w*32..w*32+31 of each array).
  auto stageH1 = [&](int kk, char* buf) {   // A1 + B1, 4 loads
    const int kb = kk * 64;
#pragma unroll
    for (int i = 0; i < 2; ++i) {
      const int rb = w * 32 + i * 16;
      const size_t ro = (size_t)rb * Hn + kb;
      stage64Bb(A1 + aOff + ro, Hn, buf + rb * 64, l);
      stage64Bb(B1 + bOff + ro, Hn, buf + 16384 + rb * 64, l);
    }
  };
  auto stageH2 = [&](int kk, char* buf) {   // A2, 2 loads
    const int kb = kk * 64;
#pragma unroll
    for (int i = 0; i < 2; ++i) {
      const int rb = w * 32 + i * 16;
      stage64Bb(A2 + aOff + (size_t)rb * Hn + kb, Hn, buf + 8192 + rb * 64, l);
    }
  };
  auto stageH3 = [&](int kk, char* buf) {   // B2, 2 loads
    const int kb = kk * 64;
#pragma unroll
    for (int i = 0; i < 2; ++i) {
      const int rb = w * 32 + i * 16;
      stage64Bb(B2 + bOff + (size_t)rb * Hn + kb, Hn, buf + 24576 + rb * 64, l);
    }
  };

  // Prologue: tile 0 fully issued (FIFO: H1,H2,H3 -> 8 outstanding).
  stageH1(0, ldsm);
  stageH2(0, ldsm);
  stageH3(0, ldsm);

  i32x4 b1f[4], a1c[4];
  for (int kk = 0; kk < 16; ++kk) {
    char* cur = ldsm + (kk & 1) * 32768;
    char* nxt = ldsm + ((kk + 1) & 1) * 32768;
    const bool pre = kk < 15;
    // ---- Phase 1: wait H1(kk); read b1,a1; issue H1(kk+1); MFMA C1 ----
    asm volatile("s_waitcnt vmcnt(4)" ::: "memory");
    __builtin_amdgcn_s_barrier();
    asm volatile("" ::: "memory");
    __builtin_amdgcn_sched_barrier(0);
#pragma unroll
    for (int ni = 0; ni < 4; ++ni) b1f[ni] = *(const i32x4*)(cur + 16384 + bo + ni * 1024);
#pragma unroll
    for (int mi = 0; mi < 4; ++mi) a1c[mi] = *(const i32x4*)(cur + ao + mi * 1024);
    if (pre) stageH1(kk + 1, nxt);
    __builtin_amdgcn_s_setprio(1);
#pragma unroll
    for (int mi = 0; mi < 4; ++mi)
#pragma unroll
      for (int ni = 0; ni < 4; ++ni)
        acc1[mi][ni] = __builtin_amdgcn_mfma_i32_16x16x64_i8(a1c[mi], b1f[ni], acc1[mi][ni], 0, 0, 0);
    __builtin_amdgcn_s_setprio(0);
    // ---- Phase 2: wait H2(kk); read a2; issue H2(kk+1); MFMA C2 ----
    if (pre) asm volatile("s_waitcnt vmcnt(6)" ::: "memory");
    else     asm volatile("s_waitcnt vmcnt(2)" ::: "memory");
    __builtin_amdgcn_s_barrier();
    asm volatile("" ::: "memory");
    __builtin_amdgcn_sched_barrier(0);
    {
      i32x4 a2f[4];
#pragma unroll
      for (int mi = 0; mi < 4; ++mi) a2f[mi] = *(const i32x4*)(cur + 8192 + ao + mi * 1024);
      if (pre) stageH2(kk + 1, nxt);
      __builtin_amdgcn_s_setprio(1);
#pragma unroll
      for (int mi = 0; mi < 4; ++mi)
#pragma unroll
        for (int ni = 0; ni < 4; ++ni)
          acc2[mi][ni] = __builtin_amdgcn_mfma_i32_16x16x64_i8(a2f[mi], b1f[ni], acc2[mi][ni], 0, 0, 0);
      __builtin_amdgcn_s_setprio(0);
    }
    // ---- Phase 3: wait H3(kk); read b2; issue H3(kk+1); MFMA C3 ----
    if (pre) asm volatile("s_waitcnt vmcnt(6)" ::: "memory");
    else     asm volatile("s_waitcnt vmcnt(0)" ::: "memory");
    __builtin_amdgcn_s_barrier();
    asm volatile("" ::: "memory");
    __builtin_amdgcn_sched_barrier(0);
    {
      i32x4 b2f[4];
#pragma unroll
      for (int ni = 0; ni < 4; ++ni) b2f[ni] = *(const i32x4*)(cur + 24576 + bo + ni * 1024);
      if (pre) stageH3(kk + 1, nxt);
      __builtin_amdgcn_s_setprio(1);
#pragma unroll
      for (int mi = 0; mi < 4; ++mi)
#pragma unroll
        for (int ni = 0; ni < 4; ++ni)
          acc2[mi][ni] = __builtin_amdgcn_mfma_i32_16x16x64_i8(a1c[mi], b2f[ni], acc2[mi][ni], 0, 0, 0);
      __builtin_amdgcn_s_setprio(0);
    }
  }
  // scores_fixed = (128*acc1 + acc2) / 256  (= true_score * 128), i16.
  const int r0 = tm * 128 + wr * 64 + (l >> 4) * 4;
  const int c0 = tn * 128 + wc * 64 + (l & 15);
#pragma unroll
  for (int mi = 0; mi < 4; ++mi)
#pragma unroll
    for (int ni = 0; ni < 4; ++ni) {
      size_t base = (size_t)(b * Sn + r0 + mi * 16) * Nn + c0 + ni * 16;
#pragma unroll
      for (int j = 0; j < 4; ++j) {
        int t = acc1[mi][ni][j] * 128 + acc2[mi][ni][j];
        int s = (int)rintf((float)t * (1.f / 256.f));
        s = s > 32767 ? 32767 : (s < -32767 ? -32767 : s);
        C[base + (size_t)j * Nn] = (short)s;
      }
    }
}

// ---------------- softmax over N on i16 scores (x128); u8 probs (x127) out ----------------
__global__ __launch_bounds__(256) void softmax_rows(const short* __restrict__ sc,
                                                    unsigned char* __restrict__ p8) {
  __shared__ float red[8];
  const size_t row = blockIdx.x;
  const short* p = sc + row * Nn;
  const int t = threadIdx.x;
  s16x8 v = ((const s16x8*)p)[t];
  float x[8];
#pragma unroll
  for (int j = 0; j < 8; ++j) x[j] = (float)v[j] * 0.0078125f;  // /128
  float m = x[0];
#pragma unroll
  for (int j = 1; j < 8; ++j) m = fmaxf(m, x[j]);
  for (int o = 32; o > 0; o >>= 1) m = fmaxf(m, __shfl_xor(m, o));
  if ((t & 63) == 0) red[t >> 6] = m;
  __syncthreads();
  m = fmaxf(fmaxf(red[0], red[1]), fmaxf(red[2], red[3]));
  float e[8], s = 0.f;
#pragma unroll
  for (int j = 0; j < 8; ++j) { e[j] = __expf(x[j] - m); s += e[j]; }
  for (int o = 32; o > 0; o >>= 1) s += __shfl_xor(s, o);
  if ((t & 63) == 0) red[4 + (t >> 6)] = s;
  __syncthreads();
  s = (red[4] + red[5]) + (red[6] + red[7]);
  const float inv = 127.f / s;
  u8x8 ob;
#pragma unroll
  for (int j = 0; j < 8; ++j) ob[j] = (unsigned char)(int)rintf(e[j] * inv);
  *(u8x8*)(p8 + row * Nn + t * 8) = ob;
}

// ---------------- GEMM2: out = residual + probs @ mem, single-level i8 ----------------
// 128x128 tile, BK=64, dbuf 2 x 16KB = 32KB LDS, 3 blocks/CU.
// Residual reconstructed from a1/a2 (seq ~ a1/16 + a2/2048, err <= 1/4096).
__global__ __launch_bounds__(256, 3) void gemm_attn(
    const char* __restrict__ P8,  // u8 probs x127, pitch 2048
    const char* __restrict__ Bt,  // i8 mem^T x16, [BC][1024][2048]
    const char* __restrict__ A1q, const char* __restrict__ A2q,
    float* __restrict__ out) {
  __shared__ __align__(16) char ldsm[32768];   // 2 buffers x {A 8KB, B 8KB}
  const int b = blockIdx.z;
  // XCD remap: grid (8,16); each XCD gets a 4(tn) x 4(tm) rectangle.
  const int lid = blockIdx.x + (blockIdx.y << 3);
  const int xcd = lid & 7, idx = lid >> 3;
  const int tn = ((xcd & 1) << 2) | (idx & 3);
  const int tm = ((xcd >> 1) << 2) | (idx >> 2);
  const int tid = threadIdx.x;
  const int w = tid >> 6, l = tid & 63;
  const int wr = w >> 1, wc = w & 1;
  const size_t aOff = (size_t)(b * Sn + tm * 128) * Nn;   // bytes, pitch 2048
  const size_t bOff = (size_t)(b * Hn + tn * 128) * Nn;

  i32x4 acc[4][4] = {};

  const int gRd = ((l >> 4) ^ ((l >> 1) & 3)) * 16;
  const int ao = (wr * 64 + (l & 15)) * 64 + gRd;
  const int bo = (wc * 64 + (l & 15)) * 64 + gRd;

  auto stageStep = [&](int kk, char* buf) {
    const int kb = kk * 64;
#pragma unroll
    for (int i = 0; i < 2; ++i) {
      const int rb = w * 32 + i * 16;
      stage64Bb(P8 + aOff + (size_t)rb * Nn + kb, Nn, buf + rb * 64, l);
      stage64Bb(Bt + bOff + (size_t)rb * Nn + kb, Nn, buf + 8192 + rb * 64, l);
    }
  };

  stageStep(0, ldsm);
  __syncthreads();

  for (int kk = 0; kk < Nn / 64; ++kk) {   // 32 K-steps
    char* cur = ldsm + (kk & 1) * 16384;
    if (kk < Nn / 64 - 1) stageStep(kk + 1, ldsm + ((kk + 1) & 1) * 16384);
    i32x4 bfr[4];
#pragma unroll
    for (int ni = 0; ni < 4; ++ni) bfr[ni] = *(const i32x4*)(cur + 8192 + bo + ni * 1024);
    i32x4 afr[4];
#pragma unroll
    for (int mi = 0; mi < 4; ++mi) afr[mi] = *(const i32x4*)(cur + ao + mi * 1024);
    __builtin_amdgcn_s_setprio(1);
#pragma unroll
    for (int mi = 0; mi < 4; ++mi)
#pragma unroll
      for (int ni = 0; ni < 4; ++ni)
        acc[mi][ni] = __builtin_amdgcn_mfma_i32_16x16x64_i8(afr[mi], bfr[ni], acc[mi][ni], 0, 0, 0);
    __builtin_amdgcn_s_setprio(0);
    if (kk < Nn / 64 - 1) __syncthreads();
  }
  const int r0 = tm * 128 + wr * 64 + (l >> 4) * 4;
  const int c0 = tn * 128 + wc * 64 + (l & 15);
  const float scl = 1.f / 2032.f;   // 1/(127*16)
#pragma unroll
  for (int mi = 0; mi < 4; ++mi)
#pragma unroll
    for (int ni = 0; ni < 4; ++ni) {
      size_t base = (size_t)(b * Sn + r0 + mi * 16) * Hn + c0 + ni * 16;
#pragma unroll
      for (int j = 0; j < 4; ++j) {
        size_t idx2 = base + (size_t)j * Hn;
        float res = (float)A1q[idx2] * 0.0625f + (float)A2q[idx2] * (1.f / 2048.f);
        out[idx2] = res + (float)acc[mi][ni][j] * scl;
      }
    }
}

// Distinctive fill if ws is too small: absmax ~12345 tells us it was this guard.
__global__ void ws_fail(float* out) {
  size_t i = (size_t)blockIdx.x * blockDim.x + threadIdx.x;
  size_t stride = (size_t)gridDim.x * blockDim.x;
  for (; i < (size_t)Bn * Sn * Hn; i += stride) out[i] = 12345.0f;
}

extern "C" void kernel_launch(void* const* d_in, const int* in_sizes, int n_in,
                              void* d_out, int out_size, void* d_ws, size_t ws_size,
                              hipStream_t stream) {
  const float* seq = (const float*)d_in[0];
  // d_in[1] (attention_mask) is unused by the reference
  const float* mem = (const float*)d_in[2];
  const int* mmask = (const int*)d_in[3];
  float* out = (float*)d_out;

  // Per-batch: a1,a2,b1,b2 (4x2 MiB) + bt2 i8 (2 MiB) + scores i16 (8 MiB) + p8 (4 MiB) = 22 MiB
  const size_t MiB = 1024 * 1024;
  const size_t perB = 22 * MiB;
  int BC = 16;
  while (BC > 1 && (size_t)BC * perB > ws_size) BC >>= 1;
  if ((size_t)BC * perB > ws_size) {
    ws_fail<<<2048, 256, 0, stream>>>(out);
    return;
  }

  char* ws = (char*)d_ws;
  const size_t SEG8 = (size_t)BC * Sn * Hn;       // BC * 2 MiB
  char* a1 = ws;
  char* a2 = ws + SEG8;
  char* b1 = ws + 2 * SEG8;
  char* b2 = ws + 3 * SEG8;
  char* bt2 = ws + 4 * SEG8;                      // 1 SEG8
  short* scores = (short*)(ws + 5 * SEG8);        // 4 SEG8 (BC x 8 MiB)
  unsigned char* p8 = (unsigned char*)(ws + 9 * SEG8);  // 2 SEG8 (BC x 4 MiB)

  for (int b0 = 0; b0 < Bn; b0 += BC) {
    const float* seqb = seq + (size_t)b0 * Sn * Hn;
    const float* memb = mem + (size_t)b0 * Nn * Hn;
    const int* mkb = mmask + (size_t)b0 * Nn;
    float* outb = out + (size_t)b0 * Sn * Hn;

    prep_seq_i8<<<dim3(BC * Sn * Hn / 4 / 256), 256, 0, stream>>>(seqb, a1, a2);
    prep_bt<<<dim3(Nn / 64, Hn / 32, BC), 256, 0, stream>>>(memb, mkb, b1, b2, bt2);
    gemm_scores<<<dim3(Nn / 128, Sn / 128, BC), 256, 0, stream>>>(a1, a2, b1, b2, scores);
    softmax_rows<<<dim3(BC * Sn), 256, 0, stream>>>(scores, p8);
    gemm_attn<<<dim3(Hn / 128, Sn / 128, BC), 256, 0, stream>>>((const char*)p8, bt2, a1, a2, outb);
  }
}

// Round 13
// 478.877 us; speedup vs baseline: 1.1289x; 1.0078x over previous
//
#include <hip/hip_runtime.h>
#include <cstdint>
#include <cstddef>

// Problem constants
#define Bn 16
#define Sn 2048
#define Hn 1024
#define Nn 2048   // n_examples * mem_len

typedef unsigned short u16;
typedef float  f32x4  __attribute__((ext_vector_type(4)));
typedef int    i32x4  __attribute__((ext_vector_type(4)));
typedef short  s16x8  __attribute__((ext_vector_type(8)));
typedef unsigned char  u8x4  __attribute__((ext_vector_type(4)));
typedef unsigned char  u8x8  __attribute__((ext_vector_type(8)));

// Two-level int8 quantization: x ~ (q1 + q2/128)/16, q1,q2 in [-127,127].
__device__ __forceinline__ void quant2(float x, char& q1, char& q2) {
  float f1 = rintf(x * 16.f);
  f1 = fminf(127.f, fmaxf(-127.f, f1));
  float r = x - f1 * 0.0625f;
  float f2 = rintf(r * 2048.f);
  f2 = fminf(127.f, fmaxf(-127.f, f2));
  q1 = (char)(int)f1;
  q2 = (char)(int)f2;
}

// Single-level i8 x16 (for GEMM2's mem operand; max err 1/32).
__device__ __forceinline__ char quant1(float x) {
  float f = rintf(x * 16.f);
  f = fminf(127.f, fmaxf(-127.f, f));
  return (char)(int)f;
}

// Stage 16 rows x 64B (one global_load_lds_dwordx4 per lane, LDS dest linear
// base + lane*16). Global source granule XOR-swizzled with (row>>1)&3 so the
// ds_read side (same XOR) is bank-conflict-free (both-sides rule #21).
__device__ __forceinline__ void stage64Bb(const char* gbase, int pitchBytes, void* ldsbase, int lane) {
  const int gsrc = (lane & 3) ^ ((lane >> 3) & 3);   // g ^ ((row_local>>1)&3), row_local = lane>>2
  const char* gp = gbase + (size_t)(lane >> 2) * pitchBytes + gsrc * 16;
  __builtin_amdgcn_global_load_lds(
      (__attribute__((address_space(1))) void*)gp,
      (__attribute__((address_space(3))) void*)ldsbase, 16, 0, 0);
}

// ---------------- prep kernels (batch-chunk local) ----------------

// seq fp32 -> two-level i8, 4 per thread.
__global__ __launch_bounds__(256) void prep_seq_i8(const float* __restrict__ seq,
                                                   char* __restrict__ a1, char* __restrict__ a2) {
  size_t i = (size_t)blockIdx.x * 256 + threadIdx.x;
  float4 v = ((const float4*)seq)[i];
  float x[4] = {v.x, v.y, v.z, v.w};
  u8x4 p1, p2;
#pragma unroll
  for (int j = 0; j < 4; ++j) {
    char q1, q2;
    quant2(x[j], q1, q2);
    p1[j] = (unsigned char)q1;
    p2[j] = (unsigned char)q2;
  }
  ((u8x4*)a1)[i] = p1;
  ((u8x4*)a2)[i] = p2;
}

// Fused memory prep: reads each mem element ONCE (as the [N][H] view), emits
//  bt1[n'][h'] i8 two-level  where flat[h'*2048+n'] = flat[r*1024+c]
//    (n' = (r&1)*1024 + c, h' = r>>1; mask index = 2h'+(n'>>10) = r)
//  bt2[h][n]  i8 x16         (transpose of the natural [N][H] view; mask mk[n])
__global__ __launch_bounds__(256) void prep_bt(const float* __restrict__ mem,
                                               const int* __restrict__ mmask,
                                               char* __restrict__ b1o, char* __restrict__ b2o,
                                               char* __restrict__ bt2) {
  __shared__ float tile[64][33];
  const int b = blockIdx.z;
  const int r0 = blockIdx.x * 64;   // 32 blocks
  const int c0 = blockIdx.y * 32;   // 32 blocks
  const int tx = threadIdx.x & 31, ty = threadIdx.x >> 5;   // 32 x 8
  const float* src = mem + (size_t)b * (Nn * Hn);
  const int* mk = mmask + b * Nn;
#pragma unroll
  for (int j = 0; j < 8; ++j) {
    int r = r0 + ty + j * 8;
    float v = src[(size_t)r * Hn + c0 + tx];
    v = mk[r] ? v : 0.f;
    tile[ty + j * 8][tx] = v;
  }
  __syncthreads();
  // bt2: region 32 h x 64 n. Lane mapping for coalesced writes: 8 lanes cover
  // 64 contiguous n-bytes of one h-row (h = t>>3, n-off = (t&7)*8).
  {
    const int hh = threadIdx.x >> 3;          // 0..31
    const int nb = (threadIdx.x & 7) * 8;     // 0..56
    u8x8 ov;
#pragma unroll
    for (int j = 0; j < 8; ++j) ov[j] = (unsigned char)quant1(tile[nb + j][hh]);
    *(u8x8*)(bt2 + (size_t)b * Hn * Nn + (size_t)(c0 + hh) * Nn + r0 + nb) = ov;
  }
  // bt1: n' = p*1024 + c0 + cl, h' = r0/2 + q*8 + j; 8 i8 pairs per thread
  {
    const int cl = threadIdx.x & 31;
    const int p  = (threadIdx.x >> 5) & 1;
    const int q  = threadIdx.x >> 6;          // 0..3
    u8x8 o1, o2;
#pragma unroll
    for (int j = 0; j < 8; ++j) {
      char q1, q2;
      quant2(tile[2 * (q * 8 + j) + p][cl], q1, q2);
      o1[j] = (unsigned char)q1;
      o2[j] = (unsigned char)q2;
    }
    size_t o = (size_t)b * Nn * Hn + (size_t)(p * 1024 + c0 + cl) * Hn + (r0 >> 1) + q * 8;
    *(u8x8*)(b1o + o) = o1;
    *(u8x8*)(b2o + o) = o2;
  }
}

// ---------------- GEMM1: scores, 2-phase counted-vmcnt schedule ----------------
// 128x128 tile, BK=64, 4 waves (2x2), dbuf 2x32KB.
// Phase A: {vmcnt lands HA(k)={A1,B1,A2}; barrier; read b1,a1,a2; stage
//           HA(k+1); MFMA C1(a1*b1->acc1) + C2(a2*b1->acc2)}
// Phase B: {vmcnt lands HB(k)={B2}; barrier; read b2; stage HB(k+1);
//           MFMA C3(a1*b2->acc2)}
// Counted waits (steady state A:vmcnt(2), B:vmcnt(6)) keep 6-8 loads in
// flight across barriers; every load gets a full K-tile of flight time.
__global__ __launch_bounds__(256, 2) void gemm_scores(
    const char* __restrict__ A1, const char* __restrict__ A2,
    const char* __restrict__ B1, const char* __restrict__ B2,
    short* __restrict__ C) {
  __shared__ __align__(16) char ldsm[65536];   // 2 buffers x {LA1|LA2|LB1|LB2} x 8KB
  const int b = blockIdx.z;
  // XCD-aware remap: each XCD's blocks form an 8(tn) x 4(tm) rectangle.
  const int lid = blockIdx.x + (blockIdx.y << 4);
  const int xcd = lid & 7, idx = lid >> 3;
  const int tn = ((xcd & 1) << 3) | (idx & 7);
  const int tm = ((xcd >> 1) << 2) | (idx >> 3);
  const int tid = threadIdx.x;
  const int w = tid >> 6, l = tid & 63;
  const int wr = w >> 1, wc = w & 1;
  const size_t aOff = (size_t)(b * Sn + tm * 128) * Hn;
  const size_t bOff = (size_t)(b * Nn + tn * 128) * Hn;

  i32x4 acc1[4][4] = {};
  i32x4 acc2[4][4] = {};

  const int gRd = ((l >> 4) ^ ((l >> 1) & 3)) * 16;
  const int ao = (wr * 64 + (l & 15)) * 64 + gRd;
  const int bo = (wc * 64 + (l & 15)) * 64 + gRd;

  // wave w owns rows w*32..w*32+31 of each 128-row array.
  auto stageHA = [&](int kk, char* buf) {   // A1 + B1 + A2, 6 loads
    const int kb = kk * 64;
#pragma unroll
    for (int i = 0; i < 2; ++i) {
      const int rb = w * 32 + i * 16;
      const size_t ro = (size_t)rb * Hn + kb;
      stage64Bb(A1 + aOff + ro, Hn, buf + rb * 64, l);
      stage64Bb(B1 + bOff + ro, Hn, buf + 16384 + rb * 64, l);
      stage64Bb(A2 + aOff + ro, Hn, buf + 8192 + rb * 64, l);
    }
  };
  auto stageHB = [&](int kk, char* buf) {   // B2, 2 loads
    const int kb = kk * 64;
#pragma unroll
    for (int i = 0; i < 2; ++i) {
      const int rb = w * 32 + i * 16;
      stage64Bb(B2 + bOff + (size_t)rb * Hn + kb, Hn, buf + 24576 + rb * 64, l);
    }
  };

  // Prologue FIFO: HA(0) 6, HB(0) 2, HA(1) 6 -> 14 outstanding.
  stageHA(0, ldsm);
  stageHB(0, ldsm);
  stageHA(1, ldsm + 32768);

  i32x4 a1c[4];
  for (int kk = 0; kk < 16; ++kk) {
    char* cur = ldsm + (kk & 1) * 32768;
    char* nxt = ldsm + ((kk + 1) & 1) * 32768;
    // ---- Phase A: land HA(kk) ----
    if (kk == 0) asm volatile("s_waitcnt vmcnt(8)" ::: "memory");
    else         asm volatile("s_waitcnt vmcnt(2)" ::: "memory");
    __builtin_amdgcn_s_barrier();
    asm volatile("" ::: "memory");
    __builtin_amdgcn_sched_barrier(0);
    {
      i32x4 b1f[4], a2f[4];
#pragma unroll
      for (int ni = 0; ni < 4; ++ni) b1f[ni] = *(const i32x4*)(cur + 16384 + bo + ni * 1024);
#pragma unroll
      for (int mi = 0; mi < 4; ++mi) a1c[mi] = *(const i32x4*)(cur + ao + mi * 1024);
#pragma unroll
      for (int mi = 0; mi < 4; ++mi) a2f[mi] = *(const i32x4*)(cur + 8192 + ao + mi * 1024);
      if (kk >= 1 && kk < 15) stageHA(kk + 1, nxt);
      __builtin_amdgcn_s_setprio(1);
#pragma unroll
      for (int mi = 0; mi < 4; ++mi)
#pragma unroll
        for (int ni = 0; ni < 4; ++ni) {
          acc1[mi][ni] = __builtin_amdgcn_mfma_i32_16x16x64_i8(a1c[mi], b1f[ni], acc1[mi][ni], 0, 0, 0);
          acc2[mi][ni] = __builtin_amdgcn_mfma_i32_16x16x64_i8(a2f[mi], b1f[ni], acc2[mi][ni], 0, 0, 0);
        }
      __builtin_amdgcn_s_setprio(0);
    }
    // ---- Phase B: land HB(kk) ----
    if (kk < 15) asm volatile("s_waitcnt vmcnt(6)" ::: "memory");
    else         asm volatile("s_waitcnt vmcnt(0)" ::: "memory");
    __builtin_amdgcn_s_barrier();
    asm volatile("" ::: "memory");
    __builtin_amdgcn_sched_barrier(0);
    {
      i32x4 b2f[4];
#pragma unroll
      for (int ni = 0; ni < 4; ++ni) b2f[ni] = *(const i32x4*)(cur + 24576 + bo + ni * 1024);
      if (kk < 15) stageHB(kk + 1, nxt);
      __builtin_amdgcn_s_setprio(1);
#pragma unroll
      for (int mi = 0; mi < 4; ++mi)
#pragma unroll
        for (int ni = 0; ni < 4; ++ni)
          acc2[mi][ni] = __builtin_amdgcn_mfma_i32_16x16x64_i8(a1c[mi], b2f[ni], acc2[mi][ni], 0, 0, 0);
      __builtin_amdgcn_s_setprio(0);
    }
  }
  // scores_fixed = (128*acc1 + acc2) / 256  (= true_score * 128), i16.
  const int r0 = tm * 128 + wr * 64 + (l >> 4) * 4;
  const int c0 = tn * 128 + wc * 64 + (l & 15);
#pragma unroll
  for (int mi = 0; mi < 4; ++mi)
#pragma unroll
    for (int ni = 0; ni < 4; ++ni) {
      size_t base = (size_t)(b * Sn + r0 + mi * 16) * Nn + c0 + ni * 16;
#pragma unroll
      for (int j = 0; j < 4; ++j) {
        int t = acc1[mi][ni][j] * 128 + acc2[mi][ni][j];
        int s = (int)rintf((float)t * (1.f / 256.f));
        s = s > 32767 ? 32767 : (s < -32767 ? -32767 : s);
        C[base + (size_t)j * Nn] = (short)s;
      }
    }
}

// ---------------- softmax over N on i16 scores (x128); u8 probs (x127) out ----------------
__global__ __launch_bounds__(256) void softmax_rows(const short* __restrict__ sc,
                                                    unsigned char* __restrict__ p8) {
  __shared__ float red[8];
  const size_t row = blockIdx.x;
  const short* p = sc + row * Nn;
  const int t = threadIdx.x;
  s16x8 v = ((const s16x8*)p)[t];
  float x[8];
#pragma unroll
  for (int j = 0; j < 8; ++j) x[j] = (float)v[j] * 0.0078125f;  // /128
  float m = x[0];
#pragma unroll
  for (int j = 1; j < 8; ++j) m = fmaxf(m, x[j]);
  for (int o = 32; o > 0; o >>= 1) m = fmaxf(m, __shfl_xor(m, o));
  if ((t & 63) == 0) red[t >> 6] = m;
  __syncthreads();
  m = fmaxf(fmaxf(red[0], red[1]), fmaxf(red[2], red[3]));
  float e[8], s = 0.f;
#pragma unroll
  for (int j = 0; j < 8; ++j) { e[j] = __expf(x[j] - m); s += e[j]; }
  for (int o = 32; o > 0; o >>= 1) s += __shfl_xor(s, o);
  if ((t & 63) == 0) red[4 + (t >> 6)] = s;
  __syncthreads();
  s = (red[4] + red[5]) + (red[6] + red[7]);
  const float inv = 127.f / s;
  u8x8 ob;
#pragma unroll
  for (int j = 0; j < 8; ++j) ob[j] = (unsigned char)(int)rintf(e[j] * inv);
  *(u8x8*)(p8 + row * Nn + t * 8) = ob;
}

// ---------------- GEMM2: out = residual + probs @ mem, single-level i8 ----------------
// 128x128 tile, BK=64, TRI-buffered LDS (3 x 16KB = 48KB) -> still 3 blocks/CU.
// stage(k+2) issued in body k; entry wait vmcnt(4) (counted, never 0 until the
// tail) + raw s_barrier -> loads fly TWO K-steps instead of being drained.
// Residual reconstructed from a1/a2 (seq ~ a1/16 + a2/2048, err <= 1/4096).
__global__ __launch_bounds__(256, 3) void gemm_attn(
    const char* __restrict__ P8,  // u8 probs x127, pitch 2048
    const char* __restrict__ Bt,  // i8 mem^T x16, [BC][1024][2048]
    const char* __restrict__ A1q, const char* __restrict__ A2q,
    float* __restrict__ out) {
  __shared__ __align__(16) char ldsm[49152];   // 3 buffers x {A 8KB, B 8KB}
  const int b = blockIdx.z;
  // XCD remap: grid (8,16); each XCD gets a 4(tn) x 4(tm) rectangle.
  const int lid = blockIdx.x + (blockIdx.y << 3);
  const int xcd = lid & 7, idx = lid >> 3;
  const int tn = ((xcd & 1) << 2) | (idx & 3);
  const int tm = ((xcd >> 1) << 2) | (idx >> 2);
  const int tid = threadIdx.x;
  const int w = tid >> 6, l = tid & 63;
  const int wr = w >> 1, wc = w & 1;
  const size_t aOff = (size_t)(b * Sn + tm * 128) * Nn;   // bytes, pitch 2048
  const size_t bOff = (size_t)(b * Hn + tn * 128) * Nn;

  i32x4 acc[4][4] = {};

  const int gRd = ((l >> 4) ^ ((l >> 1) & 3)) * 16;
  const int ao = (wr * 64 + (l & 15)) * 64 + gRd;
  const int bo = (wc * 64 + (l & 15)) * 64 + gRd;

  auto stageStep = [&](int kk, char* buf) {   // 4 loads
    const int kb = kk * 64;
#pragma unroll
    for (int i = 0; i < 2; ++i) {
      const int rb = w * 32 + i * 16;
      stage64Bb(P8 + aOff + (size_t)rb * Nn + kb, Nn, buf + rb * 64, l);
      stage64Bb(Bt + bOff + (size_t)rb * Nn + kb, Nn, buf + 8192 + rb * 64, l);
    }
  };

  // Prologue: st(0), st(1) -> 8 outstanding.
  stageStep(0, ldsm);
  stageStep(1, ldsm + 16384);

  int cb = 0;
  for (int kk = 0; kk < 32; ++kk) {   // 32 K-steps
    char* cur = ldsm + cb * 16384;
    int sb = cb + 2; if (sb >= 3) sb -= 3;
    // entry: land st(kk). Outstanding = st(kk)4 + st(kk+1)4 -> vmcnt(4);
    // tail kk=31: only st(31)4 -> vmcnt(0).
    if (kk <= 30) asm volatile("s_waitcnt vmcnt(4)" ::: "memory");
    else          asm volatile("s_waitcnt vmcnt(0)" ::: "memory");
    __builtin_amdgcn_s_barrier();
    asm volatile("" ::: "memory");
    __builtin_amdgcn_sched_barrier(0);
    i32x4 bfr[4];
#pragma unroll
    for (int ni = 0; ni < 4; ++ni) bfr[ni] = *(const i32x4*)(cur + 8192 + bo + ni * 1024);
    i32x4 afr[4];
#pragma unroll
    for (int mi = 0; mi < 4; ++mi) afr[mi] = *(const i32x4*)(cur + ao + mi * 1024);
    if (kk + 2 < 32) stageStep(kk + 2, ldsm + sb * 16384);
    __builtin_amdgcn_s_setprio(1);
#pragma unroll
    for (int mi = 0; mi < 4; ++mi)
#pragma unroll
      for (int ni = 0; ni < 4; ++ni)
        acc[mi][ni] = __builtin_amdgcn_mfma_i32_16x16x64_i8(afr[mi], bfr[ni], acc[mi][ni], 0, 0, 0);
    __builtin_amdgcn_s_setprio(0);
    cb = (cb + 1 == 3) ? 0 : cb + 1;
  }
  const int r0 = tm * 128 + wr * 64 + (l >> 4) * 4;
  const int c0 = tn * 128 + wc * 64 + (l & 15);
  const float scl = 1.f / 2032.f;   // 1/(127*16)
#pragma unroll
  for (int mi = 0; mi < 4; ++mi)
#pragma unroll
    for (int ni = 0; ni < 4; ++ni) {
      size_t base = (size_t)(b * Sn + r0 + mi * 16) * Hn + c0 + ni * 16;
#pragma unroll
      for (int j = 0; j < 4; ++j) {
        size_t idx2 = base + (size_t)j * Hn;
        float res = (float)A1q[idx2] * 0.0625f + (float)A2q[idx2] * (1.f / 2048.f);
        out[idx2] = res + (float)acc[mi][ni][j] * scl;
      }
    }
}

// Distinctive fill if ws is too small: absmax ~12345 tells us it was this guard.
__global__ void ws_fail(float* out) {
  size_t i = (size_t)blockIdx.x * blockDim.x + threadIdx.x;
  size_t stride = (size_t)gridDim.x * blockDim.x;
  for (; i < (size_t)Bn * Sn * Hn; i += stride) out[i] = 12345.0f;
}

extern "C" void kernel_launch(void* const* d_in, const int* in_sizes, int n_in,
                              void* d_out, int out_size, void* d_ws, size_t ws_size,
                              hipStream_t stream) {
  const float* seq = (const float*)d_in[0];
  // d_in[1] (attention_mask) is unused by the reference
  const float* mem = (const float*)d_in[2];
  const int* mmask = (const int*)d_in[3];
  float* out = (float*)d_out;

  // Per-batch: a1,a2,b1,b2 (4x2 MiB) + bt2 i8 (2 MiB) + scores i16 (8 MiB) + p8 (4 MiB) = 22 MiB
  const size_t MiB = 1024 * 1024;
  const size_t perB = 22 * MiB;
  int BC = 16;
  while (BC > 1 && (size_t)BC * perB > ws_size) BC >>= 1;
  if ((size_t)BC * perB > ws_size) {
    ws_fail<<<2048, 256, 0, stream>>>(out);
    return;
  }

  char* ws = (char*)d_ws;
  const size_t SEG8 = (size_t)BC * Sn * Hn;       // BC * 2 MiB
  char* a1 = ws;
  char* a2 = ws + SEG8;
  char* b1 = ws + 2 * SEG8;
  char* b2 = ws + 3 * SEG8;
  char* bt2 = ws + 4 * SEG8;                      // 1 SEG8
  short* scores = (short*)(ws + 5 * SEG8);        // 4 SEG8 (BC x 8 MiB)
  unsigned char* p8 = (unsigned char*)(ws + 9 * SEG8);  // 2 SEG8 (BC x 4 MiB)

  for (int b0 = 0; b0 < Bn; b0 += BC) {
    const float* seqb = seq + (size_t)b0 * Sn * Hn;
    const float* memb = mem + (size_t)b0 * Nn * Hn;
    const int* mkb = mmask + (size_t)b0 * Nn;
    float* outb = out + (size_t)b0 * Sn * Hn;

    prep_seq_i8<<<dim3(BC * Sn * Hn / 4 / 256), 256, 0, stream>>>(seqb, a1, a2);
    prep_bt<<<dim3(Nn / 64, Hn / 32, BC), 256, 0, stream>>>(memb, mkb, b1, b2, bt2);
    gemm_scores<<<dim3(Nn / 128, Sn / 128, BC), 256, 0, stream>>>(a1, a2, b1, b2, scores);
    softmax_rows<<<dim3(BC * Sn), 256, 0, stream>>>(scores, p8);
    gemm_attn<<<dim3(Hn / 128, Sn / 128, BC), 256, 0, stream>>>((const char*)p8, bt2, a1, a2, outb);
  }
}

// Round 14
// 399.582 us; speedup vs baseline: 1.3530x; 1.1984x over previous
//
#include <hip/hip_runtime.h>
#include <cstdint>
#include <cstddef>

// Problem constants
#define Bn 16
#define Sn 2048
#define Hn 1024
#define Nn 2048   // n_examples * mem_len

typedef unsigned short u16;
typedef float  f32x4  __attribute__((ext_vector_type(4)));
typedef int    i32x4  __attribute__((ext_vector_type(4)));
typedef short  s16x8  __attribute__((ext_vector_type(8)));
typedef unsigned char  u8x4  __attribute__((ext_vector_type(4)));
typedef unsigned char  u8x8  __attribute__((ext_vector_type(8)));

// Two-level int8 quantization: x ~ (q1 + q2/128)/16, q1,q2 in [-127,127].
__device__ __forceinline__ void quant2(float x, char& q1, char& q2) {
  float f1 = rintf(x * 16.f);
  f1 = fminf(127.f, fmaxf(-127.f, f1));
  float r = x - f1 * 0.0625f;
  float f2 = rintf(r * 2048.f);
  f2 = fminf(127.f, fmaxf(-127.f, f2));
  q1 = (char)(int)f1;
  q2 = (char)(int)f2;
}

// Single-level i8 x16 (for the gather's mem operand; max err 1/32).
__device__ __forceinline__ char quant1(float x) {
  float f = rintf(x * 16.f);
  f = fminf(127.f, fmaxf(-127.f, f));
  return (char)(int)f;
}

// Stage 16 rows x 64B (one global_load_lds_dwordx4 per lane, LDS dest linear
// base + lane*16). Global source granule XOR-swizzled with (row>>1)&3 so the
// ds_read side (same XOR) is bank-conflict-free (both-sides rule #21).
__device__ __forceinline__ void stage64Bb(const char* gbase, int pitchBytes, void* ldsbase, int lane) {
  const int gsrc = (lane & 3) ^ ((lane >> 3) & 3);   // g ^ ((row_local>>1)&3), row_local = lane>>2
  const char* gp = gbase + (size_t)(lane >> 2) * pitchBytes + gsrc * 16;
  __builtin_amdgcn_global_load_lds(
      (__attribute__((address_space(1))) void*)gp,
      (__attribute__((address_space(3))) void*)ldsbase, 16, 0, 0);
}

// ---------------- prep kernels (batch-chunk local) ----------------

// seq fp32 -> two-level i8, 4 per thread.
__global__ __launch_bounds__(256) void prep_seq_i8(const float* __restrict__ seq,
                                                   char* __restrict__ a1, char* __restrict__ a2) {
  size_t i = (size_t)blockIdx.x * 256 + threadIdx.x;
  float4 v = ((const float4*)seq)[i];
  float x[4] = {v.x, v.y, v.z, v.w};
  u8x4 p1, p2;
#pragma unroll
  for (int j = 0; j < 4; ++j) {
    char q1, q2;
    quant2(x[j], q1, q2);
    p1[j] = (unsigned char)q1;
    p2[j] = (unsigned char)q2;
  }
  ((u8x4*)a1)[i] = p1;
  ((u8x4*)a2)[i] = p2;
}

// Fused memory prep: reads each mem element ONCE (as the [N][H] view), emits
//  bt1[n'][h'] i8 two-level  where flat[h'*2048+n'] = flat[r*1024+c]
//    (n' = (r&1)*1024 + c, h' = r>>1; mask index = 2h'+(n'>>10) = r)
//  memq[n][h]  i8 x16        (natural [N][H] layout, masked; gather operand)
__global__ __launch_bounds__(256) void prep_bt(const float* __restrict__ mem,
                                               const int* __restrict__ mmask,
                                               char* __restrict__ b1o, char* __restrict__ b2o,
                                               char* __restrict__ memq) {
  __shared__ float tile[64][33];
  const int b = blockIdx.z;
  const int r0 = blockIdx.x * 64;   // 32 blocks (n dim)
  const int c0 = blockIdx.y * 32;   // 32 blocks (h dim)
  const int tx = threadIdx.x & 31, ty = threadIdx.x >> 5;   // 32 x 8
  const float* src = mem + (size_t)b * (Nn * Hn);
  const int* mk = mmask + b * Nn;
#pragma unroll
  for (int j = 0; j < 8; ++j) {
    int r = r0 + ty + j * 8;
    float v = src[(size_t)r * Hn + c0 + tx];
    v = mk[r] ? v : 0.f;
    tile[ty + j * 8][tx] = v;
  }
  __syncthreads();
  // memq: natural layout; 4 threads per n-row, 8 i8 each (32B/row region).
  {
    const int nr = threadIdx.x >> 2;          // 0..63 (n local)
    const int hb = (threadIdx.x & 3) * 8;     // 0..24 (h local)
    u8x8 ov;
#pragma unroll
    for (int j = 0; j < 8; ++j) ov[j] = (unsigned char)quant1(tile[nr][hb + j]);
    *(u8x8*)(memq + (size_t)b * Nn * Hn + (size_t)(r0 + nr) * Hn + c0 + hb) = ov;
  }
  // bt1: n' = p*1024 + c0 + cl, h' = r0/2 + q*8 + j; 8 i8 pairs per thread
  {
    const int cl = threadIdx.x & 31;
    const int p  = (threadIdx.x >> 5) & 1;
    const int q  = threadIdx.x >> 6;          // 0..3
    u8x8 o1, o2;
#pragma unroll
    for (int j = 0; j < 8; ++j) {
      char q1, q2;
      quant2(tile[2 * (q * 8 + j) + p][cl], q1, q2);
      o1[j] = (unsigned char)q1;
      o2[j] = (unsigned char)q2;
    }
    size_t o = (size_t)b * Nn * Hn + (size_t)(p * 1024 + c0 + cl) * Hn + (r0 >> 1) + q * 8;
    *(u8x8*)(b1o + o) = o1;
    *(u8x8*)(b2o + o) = o2;
  }
}

// ---------------- GEMM1: scores, 2-phase counted-vmcnt schedule (R13) ----------------
__global__ __launch_bounds__(256, 2) void gemm_scores(
    const char* __restrict__ A1, const char* __restrict__ A2,
    const char* __restrict__ B1, const char* __restrict__ B2,
    short* __restrict__ C) {
  __shared__ __align__(16) char ldsm[65536];   // 2 buffers x {LA1|LA2|LB1|LB2} x 8KB
  const int b = blockIdx.z;
  // XCD-aware remap: each XCD's blocks form an 8(tn) x 4(tm) rectangle.
  const int lid = blockIdx.x + (blockIdx.y << 4);
  const int xcd = lid & 7, idx = lid >> 3;
  const int tn = ((xcd & 1) << 3) | (idx & 7);
  const int tm = ((xcd >> 1) << 2) | (idx >> 3);
  const int tid = threadIdx.x;
  const int w = tid >> 6, l = tid & 63;
  const int wr = w >> 1, wc = w & 1;
  const size_t aOff = (size_t)(b * Sn + tm * 128) * Hn;
  const size_t bOff = (size_t)(b * Nn + tn * 128) * Hn;

  i32x4 acc1[4][4] = {};
  i32x4 acc2[4][4] = {};

  const int gRd = ((l >> 4) ^ ((l >> 1) & 3)) * 16;
  const int ao = (wr * 64 + (l & 15)) * 64 + gRd;
  const int bo = (wc * 64 + (l & 15)) * 64 + gRd;

  auto stageHA = [&](int kk, char* buf) {   // A1 + B1 + A2, 6 loads
    const int kb = kk * 64;
#pragma unroll
    for (int i = 0; i < 2; ++i) {
      const int rb = w * 32 + i * 16;
      const size_t ro = (size_t)rb * Hn + kb;
      stage64Bb(A1 + aOff + ro, Hn, buf + rb * 64, l);
      stage64Bb(B1 + bOff + ro, Hn, buf + 16384 + rb * 64, l);
      stage64Bb(A2 + aOff + ro, Hn, buf + 8192 + rb * 64, l);
    }
  };
  auto stageHB = [&](int kk, char* buf) {   // B2, 2 loads
    const int kb = kk * 64;
#pragma unroll
    for (int i = 0; i < 2; ++i) {
      const int rb = w * 32 + i * 16;
      stage64Bb(B2 + bOff + (size_t)rb * Hn + kb, Hn, buf + 24576 + rb * 64, l);
    }
  };

  stageHA(0, ldsm);
  stageHB(0, ldsm);
  stageHA(1, ldsm + 32768);

  i32x4 a1c[4];
  for (int kk = 0; kk < 16; ++kk) {
    char* cur = ldsm + (kk & 1) * 32768;
    char* nxt = ldsm + ((kk + 1) & 1) * 32768;
    // ---- Phase A ----
    if (kk == 0) asm volatile("s_waitcnt vmcnt(8)" ::: "memory");
    else         asm volatile("s_waitcnt vmcnt(2)" ::: "memory");
    __builtin_amdgcn_s_barrier();
    asm volatile("" ::: "memory");
    __builtin_amdgcn_sched_barrier(0);
    {
      i32x4 b1f[4], a2f[4];
#pragma unroll
      for (int ni = 0; ni < 4; ++ni) b1f[ni] = *(const i32x4*)(cur + 16384 + bo + ni * 1024);
#pragma unroll
      for (int mi = 0; mi < 4; ++mi) a1c[mi] = *(const i32x4*)(cur + ao + mi * 1024);
#pragma unroll
      for (int mi = 0; mi < 4; ++mi) a2f[mi] = *(const i32x4*)(cur + 8192 + ao + mi * 1024);
      if (kk >= 1 && kk < 15) stageHA(kk + 1, nxt);
      __builtin_amdgcn_s_setprio(1);
#pragma unroll
      for (int mi = 0; mi < 4; ++mi)
#pragma unroll
        for (int ni = 0; ni < 4; ++ni) {
          acc1[mi][ni] = __builtin_amdgcn_mfma_i32_16x16x64_i8(a1c[mi], b1f[ni], acc1[mi][ni], 0, 0, 0);
          acc2[mi][ni] = __builtin_amdgcn_mfma_i32_16x16x64_i8(a2f[mi], b1f[ni], acc2[mi][ni], 0, 0, 0);
        }
      __builtin_amdgcn_s_setprio(0);
    }
    // ---- Phase B ----
    if (kk < 15) asm volatile("s_waitcnt vmcnt(6)" ::: "memory");
    else         asm volatile("s_waitcnt vmcnt(0)" ::: "memory");
    __builtin_amdgcn_s_barrier();
    asm volatile("" ::: "memory");
    __builtin_amdgcn_sched_barrier(0);
    {
      i32x4 b2f[4];
#pragma unroll
      for (int ni = 0; ni < 4; ++ni) b2f[ni] = *(const i32x4*)(cur + 24576 + bo + ni * 1024);
      if (kk < 15) stageHB(kk + 1, nxt);
      __builtin_amdgcn_s_setprio(1);
#pragma unroll
      for (int mi = 0; mi < 4; ++mi)
#pragma unroll
        for (int ni = 0; ni < 4; ++ni)
          acc2[mi][ni] = __builtin_amdgcn_mfma_i32_16x16x64_i8(a1c[mi], b2f[ni], acc2[mi][ni], 0, 0, 0);
      __builtin_amdgcn_s_setprio(0);
    }
  }
  // scores_fixed = (128*acc1 + acc2) / 256  (= true_score * 128), i16.
  const int r0 = tm * 128 + wr * 64 + (l >> 4) * 4;
  const int c0 = tn * 128 + wc * 64 + (l & 15);
#pragma unroll
  for (int mi = 0; mi < 4; ++mi)
#pragma unroll
    for (int ni = 0; ni < 4; ++ni) {
      size_t base = (size_t)(b * Sn + r0 + mi * 16) * Nn + c0 + ni * 16;
#pragma unroll
      for (int j = 0; j < 4; ++j) {
        int t = acc1[mi][ni][j] * 128 + acc2[mi][ni][j];
        int s = (int)rintf((float)t * (1.f / 256.f));
        s = s > 32767 ? 32767 : (s < -32767 ? -32767 : s);
        C[base + (size_t)j * Nn] = (short)s;
      }
    }
}

// ---------------- Fused softmax + sparse gather + residual ----------------
// One 256-thread block per output row. p8 = rint(127*softmax) (bit-identical
// to the previous softmax_rows); the attention GEMM reduces to gathering the
// few rows where p8 != 0, accumulating acc += p8 * memq EXACTLY in i32 --
// identical to the dense i8 GEMM's result (zeros contribute nothing), fully
// deterministic (integer adds, index-ordered compaction).
__global__ __launch_bounds__(256) void softmax_attn(
    const short* __restrict__ sc,    // i16 scores x128, [BC*Sn][Nn]
    const char* __restrict__ memq,   // i8 mem x16, [BC][Nn][Hn]
    const char* __restrict__ A1q, const char* __restrict__ A2q,
    float* __restrict__ out) {
  __shared__ float red[8];
  __shared__ int wtot[4];
  __shared__ unsigned short sidx[128];
  __shared__ unsigned char sp[128];
  const size_t row = blockIdx.x;
  const int b = (int)(row >> 11);          // Sn = 2048 rows per batch
  const short* p = sc + row * Nn;
  const int t = threadIdx.x;
  s16x8 v = ((const s16x8*)p)[t];
  float x[8];
#pragma unroll
  for (int j = 0; j < 8; ++j) x[j] = (float)v[j] * 0.0078125f;  // /128
  float m = x[0];
#pragma unroll
  for (int j = 1; j < 8; ++j) m = fmaxf(m, x[j]);
  for (int o = 32; o > 0; o >>= 1) m = fmaxf(m, __shfl_xor(m, o));
  if ((t & 63) == 0) red[t >> 6] = m;
  __syncthreads();
  m = fmaxf(fmaxf(red[0], red[1]), fmaxf(red[2], red[3]));
  float e[8], s = 0.f;
#pragma unroll
  for (int j = 0; j < 8; ++j) { e[j] = __expf(x[j] - m); s += e[j]; }
  for (int o = 32; o > 0; o >>= 1) s += __shfl_xor(s, o);
  if ((t & 63) == 0) red[4 + (t >> 6)] = s;
  __syncthreads();
  s = (red[4] + red[5]) + (red[6] + red[7]);
  const float inv = 127.f / s;
  unsigned char r8[8];
  int cnt = 0;
#pragma unroll
  for (int j = 0; j < 8; ++j) {
    r8[j] = (unsigned char)(int)rintf(e[j] * inv);
    cnt += (r8[j] != 0);
  }
  // Deterministic exclusive scan of cnt over 256 threads (wave scan + LDS).
  int incl = cnt;
  for (int o = 1; o < 64; o <<= 1) {
    int xv = __shfl_up(incl, o);
    if ((t & 63) >= o) incl += xv;
  }
  if ((t & 63) == 63) wtot[t >> 6] = incl;
  __syncthreads();
  int base = 0;
#pragma unroll
  for (int wq = 0; wq < 4; ++wq) if (wq < (t >> 6)) base += wtot[wq];
  int pos = base + incl - cnt;
#pragma unroll
  for (int j = 0; j < 8; ++j)
    if (r8[j]) {
      if (pos < 128) { sidx[pos] = (unsigned short)(t * 8 + j); sp[pos] = r8[j]; }
      pos++;
    }
  __syncthreads();
  int total = wtot[0] + wtot[1] + wtot[2] + wtot[3];
  if (total > 128) total = 128;
  // Cooperative gather: per entry all 256 threads read 4 i8 (1KB coalesced).
  const char* mq = memq + (size_t)b * (Nn * Hn);
  int a0 = 0, a1v = 0, a2v = 0, a3 = 0;
  for (int k = 0; k < total; ++k) {
    const int n = sidx[k];
    const int pw = sp[k];
    const int wv = *(const int*)(mq + (size_t)n * Hn + (t << 2));
    a0 += pw * (int)(char)(wv);
    a1v += pw * (int)(char)(wv >> 8);
    a2v += pw * (int)(char)(wv >> 16);
    a3 += pw * (int)(char)(wv >> 24);
  }
  // Residual from a1/a2 (seq ~ a1/16 + a2/2048) + acc/(127*16).
  const size_t obase = row * Hn + (size_t)(t << 2);
  const int w1 = *(const int*)(A1q + obase);
  const int w2 = *(const int*)(A2q + obase);
  const float scl = 1.f / 2032.f;
  float4 o;
  o.x = (float)(char)(w1)       * 0.0625f + (float)(char)(w2)       * (1.f / 2048.f) + (float)a0 * scl;
  o.y = (float)(char)(w1 >> 8)  * 0.0625f + (float)(char)(w2 >> 8)  * (1.f / 2048.f) + (float)a1v * scl;
  o.z = (float)(char)(w1 >> 16) * 0.0625f + (float)(char)(w2 >> 16) * (1.f / 2048.f) + (float)a2v * scl;
  o.w = (float)(char)(w1 >> 24) * 0.0625f + (float)(char)(w2 >> 24) * (1.f / 2048.f) + (float)a3 * scl;
  *(float4*)(out + obase) = o;
}

// Distinctive fill if ws is too small: absmax ~12345 tells us it was this guard.
__global__ void ws_fail(float* out) {
  size_t i = (size_t)blockIdx.x * blockDim.x + threadIdx.x;
  size_t stride = (size_t)gridDim.x * blockDim.x;
  for (; i < (size_t)Bn * Sn * Hn; i += stride) out[i] = 12345.0f;
}

extern "C" void kernel_launch(void* const* d_in, const int* in_sizes, int n_in,
                              void* d_out, int out_size, void* d_ws, size_t ws_size,
                              hipStream_t stream) {
  const float* seq = (const float*)d_in[0];
  // d_in[1] (attention_mask) is unused by the reference
  const float* mem = (const float*)d_in[2];
  const int* mmask = (const int*)d_in[3];
  float* out = (float*)d_out;

  // Per-batch: a1,a2,b1,b2 (4x2 MiB) + memq (2 MiB) + scores i16 (8 MiB) = 18 MiB
  const size_t MiB = 1024 * 1024;
  const size_t perB = 18 * MiB;
  int BC = 16;
  while (BC > 1 && (size_t)BC * perB > ws_size) BC >>= 1;
  if ((size_t)BC * perB > ws_size) {
    ws_fail<<<2048, 256, 0, stream>>>(out);
    return;
  }

  char* ws = (char*)d_ws;
  const size_t SEG8 = (size_t)BC * Sn * Hn;       // BC * 2 MiB
  char* a1 = ws;
  char* a2 = ws + SEG8;
  char* b1 = ws + 2 * SEG8;
  char* b2 = ws + 3 * SEG8;
  char* memq = ws + 4 * SEG8;                     // 1 SEG8
  short* scores = (short*)(ws + 5 * SEG8);        // 4 SEG8 (BC x 8 MiB)

  for (int b0 = 0; b0 < Bn; b0 += BC) {
    const float* seqb = seq + (size_t)b0 * Sn * Hn;
    const float* memb = mem + (size_t)b0 * Nn * Hn;
    const int* mkb = mmask + (size_t)b0 * Nn;
    float* outb = out + (size_t)b0 * Sn * Hn;

    prep_seq_i8<<<dim3(BC * Sn * Hn / 4 / 256), 256, 0, stream>>>(seqb, a1, a2);
    prep_bt<<<dim3(Nn / 64, Hn / 32, BC), 256, 0, stream>>>(memb, mkb, b1, b2, memq);
    gemm_scores<<<dim3(Nn / 128, Sn / 128, BC), 256, 0, stream>>>(a1, a2, b1, b2, scores);
    softmax_attn<<<dim3(BC * Sn), 256, 0, stream>>>(scores, memq, a1, a2, outb);
  }
}

// Round 15
// 362.775 us; speedup vs baseline: 1.4902x; 1.1015x over previous
//
#include <hip/hip_runtime.h>
#include <cstdint>
#include <cstddef>

// Problem constants
#define Bn 16
#define Sn 2048
#define Hn 1024
#define Nn 2048   // n_examples * mem_len

typedef unsigned short u16;
typedef float  f32x4  __attribute__((ext_vector_type(4)));
typedef int    i32x4  __attribute__((ext_vector_type(4)));
typedef short  s16x8  __attribute__((ext_vector_type(8)));
typedef unsigned char  u8x4  __attribute__((ext_vector_type(4)));
typedef unsigned char  u8x8  __attribute__((ext_vector_type(8)));

// Two-level int8 quantization: x ~ (q1 + q2/128)/16, q1,q2 in [-127,127].
__device__ __forceinline__ void quant2(float x, char& q1, char& q2) {
  float f1 = rintf(x * 16.f);
  f1 = fminf(127.f, fmaxf(-127.f, f1));
  float r = x - f1 * 0.0625f;
  float f2 = rintf(r * 2048.f);
  f2 = fminf(127.f, fmaxf(-127.f, f2));
  q1 = (char)(int)f1;
  q2 = (char)(int)f2;
}

// Single-level i8 x16 (for the gather's mem operand; max err 1/32).
__device__ __forceinline__ char quant1(float x) {
  float f = rintf(x * 16.f);
  f = fminf(127.f, fmaxf(-127.f, f));
  return (char)(int)f;
}

// Stage 16 rows x 64B (one global_load_lds_dwordx4 per lane, LDS dest linear
// base + lane*16). Global source granule XOR-swizzled with (row>>1)&3 so the
// ds_read side (same XOR) is bank-conflict-free (both-sides rule #21).
__device__ __forceinline__ void stage64Bb(const char* gbase, int pitchBytes, void* ldsbase, int lane) {
  const int gsrc = (lane & 3) ^ ((lane >> 3) & 3);   // g ^ ((row_local>>1)&3), row_local = lane>>2
  const char* gp = gbase + (size_t)(lane >> 2) * pitchBytes + gsrc * 16;
  __builtin_amdgcn_global_load_lds(
      (__attribute__((address_space(1))) void*)gp,
      (__attribute__((address_space(3))) void*)ldsbase, 16, 0, 0);
}

// ---------------- prep kernels (batch-chunk local) ----------------

// seq fp32 -> two-level i8, 4 per thread.
__global__ __launch_bounds__(256) void prep_seq_i8(const float* __restrict__ seq,
                                                   char* __restrict__ a1, char* __restrict__ a2) {
  size_t i = (size_t)blockIdx.x * 256 + threadIdx.x;
  float4 v = ((const float4*)seq)[i];
  float x[4] = {v.x, v.y, v.z, v.w};
  u8x4 p1, p2;
#pragma unroll
  for (int j = 0; j < 4; ++j) {
    char q1, q2;
    quant2(x[j], q1, q2);
    p1[j] = (unsigned char)q1;
    p2[j] = (unsigned char)q2;
  }
  ((u8x4*)a1)[i] = p1;
  ((u8x4*)a2)[i] = p2;
}

// Fused memory prep: reads each mem element ONCE (as the [N][H] view), emits
//  bt1[n'][h'] i8 two-level  where flat[h'*2048+n'] = flat[r*1024+c]
//    (n' = (r&1)*1024 + c, h' = r>>1; mask index = 2h'+(n'>>10) = r)
//  memq[n][h]  i8 x16        (natural [N][H] layout, masked; gather operand)
__global__ __launch_bounds__(256) void prep_bt(const float* __restrict__ mem,
                                               const int* __restrict__ mmask,
                                               char* __restrict__ b1o, char* __restrict__ b2o,
                                               char* __restrict__ memq) {
  __shared__ float tile[64][33];
  const int b = blockIdx.z;
  const int r0 = blockIdx.x * 64;   // 32 blocks (n dim)
  const int c0 = blockIdx.y * 32;   // 32 blocks (h dim)
  const int tx = threadIdx.x & 31, ty = threadIdx.x >> 5;   // 32 x 8
  const float* src = mem + (size_t)b * (Nn * Hn);
  const int* mk = mmask + b * Nn;
#pragma unroll
  for (int j = 0; j < 8; ++j) {
    int r = r0 + ty + j * 8;
    float v = src[(size_t)r * Hn + c0 + tx];
    v = mk[r] ? v : 0.f;
    tile[ty + j * 8][tx] = v;
  }
  __syncthreads();
  // memq: natural layout; 4 threads per n-row, 8 i8 each (32B/row region).
  {
    const int nr = threadIdx.x >> 2;          // 0..63 (n local)
    const int hb = (threadIdx.x & 3) * 8;     // 0..24 (h local)
    u8x8 ov;
#pragma unroll
    for (int j = 0; j < 8; ++j) ov[j] = (unsigned char)quant1(tile[nr][hb + j]);
    *(u8x8*)(memq + (size_t)b * Nn * Hn + (size_t)(r0 + nr) * Hn + c0 + hb) = ov;
  }
  // bt1: n' = p*1024 + c0 + cl, h' = r0/2 + q*8 + j; 8 i8 pairs per thread
  {
    const int cl = threadIdx.x & 31;
    const int p  = (threadIdx.x >> 5) & 1;
    const int q  = threadIdx.x >> 6;          // 0..3
    u8x8 o1, o2;
#pragma unroll
    for (int j = 0; j < 8; ++j) {
      char q1, q2;
      quant2(tile[2 * (q * 8 + j) + p][cl], q1, q2);
      o1[j] = (unsigned char)q1;
      o2[j] = (unsigned char)q2;
    }
    size_t o = (size_t)b * Nn * Hn + (size_t)(p * 1024 + c0 + cl) * Hn + (r0 >> 1) + q * 8;
    *(u8x8*)(b1o + o) = o1;
    *(u8x8*)(b2o + o) = o2;
  }
}

// ---------------- GEMM1 (coarse): scores_c = a1.b1/256, i16 x128 ----------------
// 128x128 tile, BK=64, 4 waves (2x2). TRI-buffered LDS (3 x 16KB = 48KB,
// 3 blocks/CU), stage(k+2) issued in body k, counted vmcnt(4) entry waits
// (proven pattern from the R13 attention GEMM). 16 MFMA/K-tile.
__global__ __launch_bounds__(256, 3) void gemm_scores_coarse(
    const char* __restrict__ A1, const char* __restrict__ B1,
    short* __restrict__ C) {
  __shared__ __align__(16) char ldsm[49152];   // 3 buffers x {A 8KB | B 8KB}
  const int b = blockIdx.z;
  // XCD-aware remap: each XCD's blocks form an 8(tn) x 4(tm) rectangle.
  const int lid = blockIdx.x + (blockIdx.y << 4);
  const int xcd = lid & 7, idx = lid >> 3;
  const int tn = ((xcd & 1) << 3) | (idx & 7);
  const int tm = ((xcd >> 1) << 2) | (idx >> 3);
  const int tid = threadIdx.x;
  const int w = tid >> 6, l = tid & 63;
  const int wr = w >> 1, wc = w & 1;
  const size_t aOff = (size_t)(b * Sn + tm * 128) * Hn;
  const size_t bOff = (size_t)(b * Nn + tn * 128) * Hn;

  i32x4 acc[4][4] = {};

  const int gRd = ((l >> 4) ^ ((l >> 1) & 3)) * 16;
  const int ao = (wr * 64 + (l & 15)) * 64 + gRd;
  const int bo = (wc * 64 + (l & 15)) * 64 + gRd;

  auto stageStep = [&](int kk, char* buf) {   // 4 loads per lane
    const int kb = kk * 64;
#pragma unroll
    for (int i = 0; i < 2; ++i) {
      const int rb = w * 32 + i * 16;
      const size_t ro = (size_t)rb * Hn + kb;
      stage64Bb(A1 + aOff + ro, Hn, buf + rb * 64, l);
      stage64Bb(B1 + bOff + ro, Hn, buf + 8192 + rb * 64, l);
    }
  };

  stageStep(0, ldsm);
  stageStep(1, ldsm + 16384);

  int cb = 0;
  for (int kk = 0; kk < 16; ++kk) {
    char* cur = ldsm + cb * 16384;
    int sb = cb + 2; if (sb >= 3) sb -= 3;
    if (kk <= 14) asm volatile("s_waitcnt vmcnt(4)" ::: "memory");
    else          asm volatile("s_waitcnt vmcnt(0)" ::: "memory");
    __builtin_amdgcn_s_barrier();
    asm volatile("" ::: "memory");
    __builtin_amdgcn_sched_barrier(0);
    i32x4 bfr[4];
#pragma unroll
    for (int ni = 0; ni < 4; ++ni) bfr[ni] = *(const i32x4*)(cur + 8192 + bo + ni * 1024);
    i32x4 afr[4];
#pragma unroll
    for (int mi = 0; mi < 4; ++mi) afr[mi] = *(const i32x4*)(cur + ao + mi * 1024);
    if (kk + 2 < 16) stageStep(kk + 2, ldsm + sb * 16384);
    __builtin_amdgcn_s_setprio(1);
#pragma unroll
    for (int mi = 0; mi < 4; ++mi)
#pragma unroll
      for (int ni = 0; ni < 4; ++ni)
        acc[mi][ni] = __builtin_amdgcn_mfma_i32_16x16x64_i8(afr[mi], bfr[ni], acc[mi][ni], 0, 0, 0);
    __builtin_amdgcn_s_setprio(0);
    cb = (cb + 1 == 3) ? 0 : cb + 1;
  }
  // coarse_fixed = acc/2 (= coarse_score * 128), i16.
  const int r0 = tm * 128 + wr * 64 + (l >> 4) * 4;
  const int c0 = tn * 128 + wc * 64 + (l & 15);
#pragma unroll
  for (int mi = 0; mi < 4; ++mi)
#pragma unroll
    for (int ni = 0; ni < 4; ++ni) {
      size_t base = (size_t)(b * Sn + r0 + mi * 16) * Nn + c0 + ni * 16;
#pragma unroll
      for (int j = 0; j < 4; ++j) {
        int s = (int)rintf((float)acc[mi][ni][j] * 0.5f);
        s = s > 32767 ? 32767 : (s < -32767 ? -32767 : s);
        C[base + (size_t)j * Nn] = (short)s;
      }
    }
}

// ---------------- Fused softmax + refinement + sparse gather + residual ----------------
// One 256-thread block per output row. Coarse scores (err std ~0.8) select
// candidates within 11 of the coarse max (expected ~2, cap 64). Candidates
// are refined with the exact cross term (a1.b2 + a2.b1)/32768 -- same error
// class as the old full two-level scores. Softmax over refined candidates
// (excluded tail contributes <= e^-8 to the denominator); p8 = rint(127*p);
// integer gather of memq rows where p8 != 0; residual from a1/a2.
__global__ __launch_bounds__(256) void softmax_attn(
    const short* __restrict__ sc,    // i16 coarse scores x128, [BC*Sn][Nn]
    const char* __restrict__ memq,   // i8 mem x16, [BC][Nn][Hn]
    const char* __restrict__ B1q, const char* __restrict__ B2q,  // bt1 two-level
    const char* __restrict__ A1q, const char* __restrict__ A2q,
    float* __restrict__ out) {
  __shared__ int redi[4];
  __shared__ int wtot[4];
  __shared__ unsigned short sidx[64];
  __shared__ int scand[64];
  __shared__ int scross[64];
  __shared__ unsigned char sp[64];
  const size_t row = blockIdx.x;
  const int b = (int)(row >> 11);          // Sn = 2048 rows per batch
  const int t = threadIdx.x;
  const int w = t >> 6, l = t & 63;
  s16x8 v = ((const s16x8*)(sc + row * Nn))[t];
  // coarse row max
  int mymax = (int)v[0];
#pragma unroll
  for (int j = 1; j < 8; ++j) mymax = max(mymax, (int)v[j]);
  for (int o = 32; o > 0; o >>= 1) mymax = max(mymax, __shfl_xor(mymax, o));
  if (l == 0) redi[w] = mymax;
  __syncthreads();
  const int mc = max(max(redi[0], redi[1]), max(redi[2], redi[3]));
  const int thresh = mc - 1408;            // 11 * 128
  // count + deterministic exclusive scan over 256 threads
  int cnt = 0;
#pragma unroll
  for (int j = 0; j < 8; ++j) cnt += ((int)v[j] >= thresh);
  int incl = cnt;
  for (int o = 1; o < 64; o <<= 1) {
    int xv = __shfl_up(incl, o);
    if (l >= o) incl += xv;
  }
  if (l == 63) wtot[w] = incl;
  __syncthreads();
  int base = 0;
#pragma unroll
  for (int wq = 0; wq < 4; ++wq) if (wq < w) base += wtot[wq];
  int pos = base + incl - cnt;
#pragma unroll
  for (int j = 0; j < 8; ++j)
    if ((int)v[j] >= thresh) {
      if (pos < 64) { sidx[pos] = (unsigned short)(t * 8 + j); scand[pos] = (int)v[j]; }
      pos++;
    }
  __syncthreads();
  int total = wtot[0] + wtot[1] + wtot[2] + wtot[3];
  if (total > 64) total = 64;
  // Refinement: wave w handles candidate k0+w; lane l covers k-slice l*16..+15.
  const i32x4 a1s = *(const i32x4*)(A1q + row * (size_t)Hn + l * 16);
  const i32x4 a2s = *(const i32x4*)(A2q + row * (size_t)Hn + l * 16);
  for (int k0 = 0; k0 < total; k0 += 4) {
    const int k = k0 + w;
    int cross = 0;
    if (k < total) {
      const size_t nb = ((size_t)b * Nn + sidx[k]) * Hn + l * 16;
      const i32x4 b1v = *(const i32x4*)(B1q + nb);
      const i32x4 b2v = *(const i32x4*)(B2q + nb);
#pragma unroll
      for (int r = 0; r < 4; ++r)
#pragma unroll
        for (int s8 = 0; s8 < 4; ++s8) {
          const int sh = s8 * 8;
          cross += (int)(char)(a1s[r] >> sh) * (int)(char)(b2v[r] >> sh)
                 + (int)(char)(a2s[r] >> sh) * (int)(char)(b1v[r] >> sh);
        }
    }
    for (int o = 32; o > 0; o >>= 1) cross += __shfl_xor(cross, o);
    if (l == 0 && k < total) scross[k] = cross;
  }
  __syncthreads();
  // p8 over refined candidates (threads 0..total-1 write; all compute m,s)
  if (t < total) {
    float mref = -1e30f;
    for (int k = 0; k < total; ++k) {
      float f = (float)scand[k] * 0.0078125f + (float)scross[k] * (1.f / 32768.f);
      mref = fmaxf(mref, f);
    }
    float s = 0.f;
    for (int k = 0; k < total; ++k) {
      float f = (float)scand[k] * 0.0078125f + (float)scross[k] * (1.f / 32768.f);
      s += __expf(f - mref);
    }
    const float fme = (float)scand[t] * 0.0078125f + (float)scross[t] * (1.f / 32768.f);
    sp[t] = (unsigned char)(int)rintf(127.f * __expf(fme - mref) / s);
  }
  __syncthreads();
  // Cooperative gather: per nonzero candidate all 256 threads read 4 i8.
  const char* mq = memq + (size_t)b * (Nn * Hn);
  int a0 = 0, a1v = 0, a2v = 0, a3 = 0;
  for (int k = 0; k < total; ++k) {
    const int pw = sp[k];
    if (!pw) continue;
    const int n = sidx[k];
    const int wv = *(const int*)(mq + (size_t)n * Hn + (t << 2));
    a0 += pw * (int)(char)(wv);
    a1v += pw * (int)(char)(wv >> 8);
    a2v += pw * (int)(char)(wv >> 16);
    a3 += pw * (int)(char)(wv >> 24);
  }
  // Residual from a1/a2 (seq ~ a1/16 + a2/2048) + acc/(127*16).
  const size_t obase = row * Hn + (size_t)(t << 2);
  const int w1 = *(const int*)(A1q + obase);
  const int w2 = *(const int*)(A2q + obase);
  const float scl = 1.f / 2032.f;
  float4 o;
  o.x = (float)(char)(w1)       * 0.0625f + (float)(char)(w2)       * (1.f / 2048.f) + (float)a0 * scl;
  o.y = (float)(char)(w1 >> 8)  * 0.0625f + (float)(char)(w2 >> 8)  * (1.f / 2048.f) + (float)a1v * scl;
  o.z = (float)(char)(w1 >> 16) * 0.0625f + (float)(char)(w2 >> 16) * (1.f / 2048.f) + (float)a2v * scl;
  o.w = (float)(char)(w1 >> 24) * 0.0625f + (float)(char)(w2 >> 24) * (1.f / 2048.f) + (float)a3 * scl;
  *(float4*)(out + obase) = o;
}

// Distinctive fill if ws is too small: absmax ~12345 tells us it was this guard.
__global__ void ws_fail(float* out) {
  size_t i = (size_t)blockIdx.x * blockDim.x + threadIdx.x;
  size_t stride = (size_t)gridDim.x * blockDim.x;
  for (; i < (size_t)Bn * Sn * Hn; i += stride) out[i] = 12345.0f;
}

extern "C" void kernel_launch(void* const* d_in, const int* in_sizes, int n_in,
                              void* d_out, int out_size, void* d_ws, size_t ws_size,
                              hipStream_t stream) {
  const float* seq = (const float*)d_in[0];
  // d_in[1] (attention_mask) is unused by the reference
  const float* mem = (const float*)d_in[2];
  const int* mmask = (const int*)d_in[3];
  float* out = (float*)d_out;

  // Per-batch: a1,a2,b1,b2 (4x2 MiB) + memq (2 MiB) + scores i16 (8 MiB) = 18 MiB
  const size_t MiB = 1024 * 1024;
  const size_t perB = 18 * MiB;
  int BC = 16;
  while (BC > 1 && (size_t)BC * perB > ws_size) BC >>= 1;
  if ((size_t)BC * perB > ws_size) {
    ws_fail<<<2048, 256, 0, stream>>>(out);
    return;
  }

  char* ws = (char*)d_ws;
  const size_t SEG8 = (size_t)BC * Sn * Hn;       // BC * 2 MiB
  char* a1 = ws;
  char* a2 = ws + SEG8;
  char* b1 = ws + 2 * SEG8;
  char* b2 = ws + 3 * SEG8;
  char* memq = ws + 4 * SEG8;                     // 1 SEG8
  short* scores = (short*)(ws + 5 * SEG8);        // 4 SEG8 (BC x 8 MiB)

  for (int b0 = 0; b0 < Bn; b0 += BC) {
    const float* seqb = seq + (size_t)b0 * Sn * Hn;
    const float* memb = mem + (size_t)b0 * Nn * Hn;
    const int* mkb = mmask + (size_t)b0 * Nn;
    float* outb = out + (size_t)b0 * Sn * Hn;

    prep_seq_i8<<<dim3(BC * Sn * Hn / 4 / 256), 256, 0, stream>>>(seqb, a1, a2);
    prep_bt<<<dim3(Nn / 64, Hn / 32, BC), 256, 0, stream>>>(memb, mkb, b1, b2, memq);
    gemm_scores_coarse<<<dim3(Nn / 128, Sn / 128, BC), 256, 0, stream>>>(a1, b1, scores);
    softmax_attn<<<dim3(BC * Sn), 256, 0, stream>>>(scores, memq, b1, b2, a1, a2, outb);
  }
}